// Round 1
// baseline (274.165 us; speedup 1.0000x reference)
//
#include <hip/hip_runtime.h>

typedef unsigned short u16;
typedef unsigned int u32;
typedef short bf16x8 __attribute__((ext_vector_type(8)));
typedef float f32x4 __attribute__((ext_vector_type(4)));

__device__ __forceinline__ u16 f2bf(float f) {
  union { float f; u32 u; } v; v.f = f;
  u32 r = v.u + 0x7fffu + ((v.u >> 16) & 1u);
  return (u16)(r >> 16);
}

__device__ __forceinline__ void gld_lds16(const u16* g, u16* l) {
  __builtin_amdgcn_global_load_lds(
      (__attribute__((address_space(1))) u32*)(g),
      (__attribute__((address_space(3))) u32*)(l),
      16, 0, 0);
}

// LDS fragment read with XOR-16B swizzle (rows of 64 bf16 = 8 chunks of 16B).
// Physical chunk = logical_chunk ^ (row & 7); staging uses the same map.
__device__ __forceinline__ bf16x8 ldsfrag(const u16* base, int row, int c8) {
  return *(const bf16x8*)(base + row * 64 + ((c8 ^ (row & 7)) << 3));
}

// ---------------- fp32 -> bf16 convert (x) ----------------
__global__ __launch_bounds__(256) void k_cvt(const float* __restrict__ s, u16* __restrict__ d) {
  int i = (blockIdx.x * 256 + threadIdx.x) * 8;
  const float4* p = (const float4*)(s + i);
  float4 a = p[0], b = p[1];
  uint4 o;
  o.x = (u32)f2bf(a.x) | ((u32)f2bf(a.y) << 16);
  o.y = (u32)f2bf(a.z) | ((u32)f2bf(a.w) << 16);
  o.z = (u32)f2bf(b.x) | ((u32)f2bf(b.y) << 16);
  o.w = (u32)f2bf(b.z) | ((u32)f2bf(b.w) << 16);
  *(uint4*)(d + i) = o;
}

// ---------------- fp32 [rows][cols] -> bf16 transposed [cols][rows] ----------------
__global__ __launch_bounds__(256) void k_tr(const float* __restrict__ s, u16* __restrict__ d,
                                            int rows, int cols) {
  __shared__ float t[64][65];
  int c0 = blockIdx.x * 64, r0 = blockIdx.y * 64;
  int tx = threadIdx.x & 63, ty = threadIdx.x >> 6;
#pragma unroll
  for (int i = ty; i < 64; i += 4)
    t[i][tx] = s[(size_t)(r0 + i) * cols + c0 + tx];
  __syncthreads();
#pragma unroll
  for (int i = ty; i < 64; i += 4)
    d[(size_t)(c0 + i) * rows + r0 + tx] = f2bf(t[tx][i]);
}

// ---------------- shared 128x128x(K) bf16 MFMA GEMM core ----------------
// A [M][K] row-major bf16, Bt [N][K] row-major bf16 (i.e. B transposed).
// Block 256 thr = 4 waves in 2x2; each wave 64x64 via 4x4 mfma_f32_16x16x32_bf16.
__device__ __forceinline__ void gemm_core(const u16* __restrict__ A, const u16* __restrict__ Bt,
                                          const int K, const int m0, const int n0,
                                          u16* sA, u16* sB, f32x4 acc[4][4]) {
  const int tid = threadIdx.x;
  const int lane = tid & 63, w = tid >> 6;
  const int wm = (w >> 1) << 6, wn = (w & 1) << 6;
  const int lr = lane & 15, lq = lane >> 4;
  const int srow = tid >> 3;                       // staging row 0..31 (per round +32)
  const int gcol = ((tid & 7) ^ (srow & 7)) << 3;  // swizzled 16B chunk within row
  const u16* ag = A + (size_t)(m0 + srow) * K + gcol;
  const u16* bg = Bt + (size_t)(n0 + srow) * K + gcol;
  u16* la = sA + w * 512;
  u16* lb = sB + w * 512;

  for (int k0 = 0; k0 < K; k0 += 64) {
    __syncthreads();  // previous tile's LDS reads done
#pragma unroll
    for (int r = 0; r < 4; ++r) {
      gld_lds16(ag + (size_t)r * 32 * K + k0, la + r * 2048);
      gld_lds16(bg + (size_t)r * 32 * K + k0, lb + r * 2048);
    }
    __syncthreads();  // compiler drains vmcnt before barrier
#pragma unroll
    for (int kk = 0; kk < 64; kk += 32) {
      const int c8 = (kk >> 3) + lq;
      bf16x8 af[4], bfr[4];
#pragma unroll
      for (int i = 0; i < 4; ++i) {
        af[i] = ldsfrag(sA, wm + i * 16 + lr, c8);
        bfr[i] = ldsfrag(sB, wn + i * 16 + lr, c8);
      }
#pragma unroll
      for (int mi = 0; mi < 4; ++mi)
#pragma unroll
        for (int ni = 0; ni < 4; ++ni)
          acc[mi][ni] = __builtin_amdgcn_mfma_f32_16x16x32_bf16(af[mi], bfr[ni], acc[mi][ni], 0, 0, 0);
    }
  }
}

// ---------------- GEMM1: qkv = x @ W_attn + b, scattered to q/k/vt head layouts ----------------
__global__ __launch_bounds__(256) void k_gemm_qkv(const u16* __restrict__ xb,
                                                  const u16* __restrict__ Wt,
                                                  const float* __restrict__ bias,
                                                  u16* __restrict__ qb, u16* __restrict__ kb,
                                                  u16* __restrict__ vtb) {
  __shared__ u16 sA[128 * 64], sB[128 * 64];
  f32x4 acc[4][4];
#pragma unroll
  for (int mi = 0; mi < 4; ++mi)
#pragma unroll
    for (int ni = 0; ni < 4; ++ni) acc[mi][ni] = (f32x4){0.f, 0.f, 0.f, 0.f};
  const int m0 = blockIdx.y * 128, n0 = blockIdx.x * 128;
  gemm_core(xb, Wt, 1024, m0, n0, sA, sB, acc);

  const int lane = threadIdx.x & 63, w = threadIdx.x >> 6;
  const int wm = (w >> 1) << 6, wn = (w & 1) << 6, lr = lane & 15, lq = lane >> 4;
#pragma unroll
  for (int mi = 0; mi < 4; ++mi) {
    int gm = m0 + wm + mi * 16 + lq * 4;
#pragma unroll
    for (int ni = 0; ni < 4; ++ni) {
      int gn = n0 + wn + ni * 16 + lr;
      float bv = bias[gn];
      int which = gn >> 10, head = (gn >> 6) & 15, hd = gn & 63;
#pragma unroll
      for (int r = 0; r < 4; ++r) {
        int row = gm + r;
        int b = row >> 11, t = row & 2047;
        float v = acc[mi][ni][r] + bv;
        size_t bh = (size_t)(b * 16 + head);
        if (which == 0)
          qb[(bh * 2048 + t) * 64 + hd] = f2bf(v * 0.125f);  // fold 1/sqrt(64), exact in bf16
        else if (which == 1)
          kb[(bh * 2048 + t) * 64 + hd] = f2bf(v);
        else
          vtb[(bh * 64 + hd) * 2048 + t] = f2bf(v);  // V stored head-transposed [hd][T]
      }
    }
  }
}

// ---------------- flash attention: BQ=128 (4 waves x 32 rows), BKV=64, hd=64 ----------------
__global__ __launch_bounds__(256) void k_attn(const u16* __restrict__ qb, const u16* __restrict__ kb,
                                              const u16* __restrict__ vtb, u16* __restrict__ yb) {
  __shared__ u16 sQ[128 * 64];
  __shared__ u16 sK[64 * 64];
  __shared__ u16 sV[64 * 64];   // [hd][kv]
  __shared__ u16 sP[128 * 72];  // padded +8 elems/row: 2-way-max bank aliasing

  const int tid = threadIdx.x;
  const int lane = tid & 63, w = tid >> 6;
  const int lr = lane & 15, lq = lane >> 4;
  const int bh = blockIdx.y;
  const int qt = 15 - blockIdx.x;  // heavy tiles dispatched first
  const int q0 = qt << 7;

  const u16* qh = qb + (size_t)bh * (2048 * 64);
  const u16* kh = kb + (size_t)bh * (2048 * 64);
  const u16* vh = vtb + (size_t)bh * (64 * 2048);

  const int srow = tid >> 3;
  const int gcol = ((tid & 7) ^ (srow & 7)) << 3;

  {  // Q tile, 16KB, 4 rounds
    u16* lqs = sQ + w * 512;
    const u16* gq = qh + (size_t)(q0 + srow) * 64 + gcol;
#pragma unroll
    for (int r = 0; r < 4; ++r) gld_lds16(gq + (size_t)(r * 32) * 64, lqs + r * 2048);
  }

  f32x4 o[2][4];
  float mrow[2][4], lrow[2][4];
#pragma unroll
  for (int mi = 0; mi < 2; ++mi)
#pragma unroll
    for (int j = 0; j < 4; ++j) {
      o[mi][j] = (f32x4){0.f, 0.f, 0.f, 0.f};
      mrow[mi][j] = -1e30f;
      lrow[mi][j] = 0.f;
    }

  const int ntiles = qt * 2 + 2;
  for (int it = 0; it < ntiles; ++it) {
    const int kv0 = it << 6;
    __syncthreads();  // prior tile's K/V reads complete
    {
      u16* lk = sK + w * 512;
      u16* lv = sV + w * 512;
      const u16* gk = kh + (size_t)(kv0 + srow) * 64 + gcol;
      const u16* gv = vh + (size_t)srow * 2048 + kv0 + gcol;
#pragma unroll
      for (int r = 0; r < 2; ++r) {
        gld_lds16(gk + (size_t)(r * 32) * 64, lk + r * 2048);
        gld_lds16(gv + (size_t)(r * 32) * 2048, lv + r * 2048);
      }
    }
    __syncthreads();

    // S = Q K^T  (wave w owns rows w*32..+32, all 64 kv cols)
    f32x4 s[2][4];
#pragma unroll
    for (int mi = 0; mi < 2; ++mi)
#pragma unroll
      for (int nj = 0; nj < 4; ++nj) s[mi][nj] = (f32x4){0.f, 0.f, 0.f, 0.f};
#pragma unroll
    for (int kk = 0; kk < 64; kk += 32) {
      const int c8 = (kk >> 3) + lq;
      bf16x8 qa[2], kf[4];
      qa[0] = ldsfrag(sQ, w * 32 + lr, c8);
      qa[1] = ldsfrag(sQ, w * 32 + 16 + lr, c8);
#pragma unroll
      for (int nj = 0; nj < 4; ++nj) kf[nj] = ldsfrag(sK, nj * 16 + lr, c8);
#pragma unroll
      for (int mi = 0; mi < 2; ++mi)
#pragma unroll
        for (int nj = 0; nj < 4; ++nj)
          s[mi][nj] = __builtin_amdgcn_mfma_f32_16x16x32_bf16(qa[mi], kf[nj], s[mi][nj], 0, 0, 0);
    }

    if (kv0 + 64 > q0) {  // causal mask only on diagonal tiles
#pragma unroll
      for (int mi = 0; mi < 2; ++mi) {
        int qrow = q0 + w * 32 + mi * 16 + lq * 4;
#pragma unroll
        for (int nj = 0; nj < 4; ++nj) {
          int col = kv0 + nj * 16 + lr;
#pragma unroll
          for (int r = 0; r < 4; ++r)
            if (col > qrow + r) s[mi][nj][r] = -1e30f;
        }
      }
    }

    // online softmax; C-layout row = lq*4+r, 16 lanes per row-group
#pragma unroll
    for (int mi = 0; mi < 2; ++mi) {
      float al[4];
#pragma unroll
      for (int r = 0; r < 4; ++r) {
        float mx = fmaxf(fmaxf(s[mi][0][r], s[mi][1][r]), fmaxf(s[mi][2][r], s[mi][3][r]));
#pragma unroll
        for (int off = 1; off < 16; off <<= 1) mx = fmaxf(mx, __shfl_xor(mx, off, 64));
        float mn = fmaxf(mrow[mi][r], mx);
        al[r] = __expf(mrow[mi][r] - mn);
        mrow[mi][r] = mn;
      }
#pragma unroll
      for (int nj = 0; nj < 4; ++nj)
#pragma unroll
        for (int r = 0; r < 4; ++r) o[mi][nj][r] *= al[r];
      float rs[4] = {0.f, 0.f, 0.f, 0.f};
#pragma unroll
      for (int nj = 0; nj < 4; ++nj)
#pragma unroll
        for (int r = 0; r < 4; ++r) {
          float p = __expf(s[mi][nj][r] - mrow[mi][r]);
          s[mi][nj][r] = p;
          rs[r] += p;
        }
#pragma unroll
      for (int r = 0; r < 4; ++r) {
        float t = rs[r];
#pragma unroll
        for (int off = 1; off < 16; off <<= 1) t += __shfl_xor(t, off, 64);
        lrow[mi][r] = lrow[mi][r] * al[r] + t;
      }
      // P -> LDS (own wave's rows only; no cross-wave sync needed)
#pragma unroll
      for (int nj = 0; nj < 4; ++nj)
#pragma unroll
        for (int r = 0; r < 4; ++r)
          sP[(w * 32 + mi * 16 + lq * 4 + r) * 72 + nj * 16 + lr] = f2bf(s[mi][nj][r]);
    }
    asm volatile("s_waitcnt lgkmcnt(0)" ::: "memory");

    // O += P V   (A = P from sP, B = V^T from sV)
#pragma unroll
    for (int kk = 0; kk < 64; kk += 32) {
      const int c8 = (kk >> 3) + lq;
      bf16x8 pa[2], vf[4];
      pa[0] = *(const bf16x8*)(sP + (w * 32 + lr) * 72 + kk + lq * 8);
      pa[1] = *(const bf16x8*)(sP + (w * 32 + 16 + lr) * 72 + kk + lq * 8);
#pragma unroll
      for (int nj = 0; nj < 4; ++nj) vf[nj] = ldsfrag(sV, nj * 16 + lr, c8);
#pragma unroll
      for (int mi = 0; mi < 2; ++mi)
#pragma unroll
        for (int nj = 0; nj < 4; ++nj)
          o[mi][nj] = __builtin_amdgcn_mfma_f32_16x16x32_bf16(pa[mi], vf[nj], o[mi][nj], 0, 0, 0);
    }
  }

  // y[b][t][h*64+hd] bf16
  const int b = bh >> 4, h = bh & 15;
#pragma unroll
  for (int mi = 0; mi < 2; ++mi)
#pragma unroll
    for (int r = 0; r < 4; ++r) {
      float inv = 1.0f / lrow[mi][r];
      int row = q0 + w * 32 + mi * 16 + lq * 4 + r;
      size_t base = ((size_t)(b * 2048 + row)) * 1024 + h * 64;
#pragma unroll
      for (int nj = 0; nj < 4; ++nj) yb[base + nj * 16 + lr] = f2bf(o[mi][nj][r] * inv);
    }
}

// ---------------- GEMM2: out = y @ W_proj + b (fp32 out) ----------------
__global__ __launch_bounds__(256) void k_gemm_proj(const u16* __restrict__ ybuf,
                                                   const u16* __restrict__ Wt,
                                                   const float* __restrict__ bias,
                                                   float* __restrict__ out) {
  __shared__ u16 sA[128 * 64], sB[128 * 64];
  f32x4 acc[4][4];
#pragma unroll
  for (int mi = 0; mi < 4; ++mi)
#pragma unroll
    for (int ni = 0; ni < 4; ++ni) acc[mi][ni] = (f32x4){0.f, 0.f, 0.f, 0.f};
  const int m0 = blockIdx.y * 128, n0 = blockIdx.x * 128;
  gemm_core(ybuf, Wt, 1024, m0, n0, sA, sB, acc);

  const int lane = threadIdx.x & 63, w = threadIdx.x >> 6;
  const int wm = (w >> 1) << 6, wn = (w & 1) << 6, lr = lane & 15, lq = lane >> 4;
#pragma unroll
  for (int mi = 0; mi < 4; ++mi) {
    int gm = m0 + wm + mi * 16 + lq * 4;
#pragma unroll
    for (int ni = 0; ni < 4; ++ni) {
      int gn = n0 + wn + ni * 16 + lr;
      float bv = bias[gn];
#pragma unroll
      for (int r = 0; r < 4; ++r) out[(size_t)(gm + r) * 1024 + gn] = acc[mi][ni][r] + bv;
    }
  }
}

extern "C" void kernel_launch(void* const* d_in, const int* in_sizes, int n_in,
                              void* d_out, int out_size, void* d_ws, size_t ws_size,
                              hipStream_t stream) {
  const float* x = (const float*)d_in[0];       // [2,2048,1024]
  const float* W_attn = (const float*)d_in[1];  // [1024,3072]
  const float* b_attn = (const float*)d_in[2];  // [3072]
  const float* W_proj = (const float*)d_in[3];  // [1024,1024]
  const float* b_proj = (const float*)d_in[4];  // [1024]
  float* out = (float*)d_out;                   // [2,2048,1024] fp32

  u16* ws = (u16*)d_ws;
  u16* xb = ws;                   // 4096x1024 bf16
  u16* WaT = ws + 4194304;        // 3072x1024 (W_attn^T)
  u16* WpT = ws + 7340032;        // 1024x1024 (W_proj^T)
  u16* qbuf = ws + 8388608;       // [32][2048][64]
  u16* kbuf = ws + 12582912;      // [32][2048][64]
  u16* vtb = ws + 16777216;       // [32][64][2048]
  u16* ybuf = ws + 20971520;      // [4096][1024]

  k_cvt<<<dim3(2048), dim3(256), 0, stream>>>(x, xb);
  k_tr<<<dim3(48, 16), dim3(256), 0, stream>>>(W_attn, WaT, 1024, 3072);
  k_tr<<<dim3(16, 16), dim3(256), 0, stream>>>(W_proj, WpT, 1024, 1024);
  k_gemm_qkv<<<dim3(24, 32), dim3(256), 0, stream>>>(xb, WaT, b_attn, qbuf, kbuf, vtb);
  k_attn<<<dim3(16, 32), dim3(256), 0, stream>>>(qbuf, kbuf, vtb, ybuf);
  k_gemm_proj<<<dim3(8, 32), dim3(256), 0, stream>>>(ybuf, WpT, b_proj, out);
}

// Round 2
// 247.702 us; speedup vs baseline: 1.1068x; 1.1068x over previous
//
#include <hip/hip_runtime.h>

typedef unsigned short u16;
typedef unsigned int u32;
typedef short bf16x8 __attribute__((ext_vector_type(8)));
typedef float f32x4 __attribute__((ext_vector_type(4)));

__device__ __forceinline__ u16 f2bf(float f) {
  union { float f; u32 u; } v; v.f = f;
  u32 r = v.u + 0x7fffu + ((v.u >> 16) & 1u);
  return (u16)(r >> 16);
}

__device__ __forceinline__ void gld_lds16(const u16* g, u16* l) {
  __builtin_amdgcn_global_load_lds(
      (__attribute__((address_space(1))) u32*)(g),
      (__attribute__((address_space(3))) u32*)(l),
      16, 0, 0);
}

// LDS fragment read with XOR-16B swizzle (rows of 64 bf16 = 8 chunks of 16B).
// Physical chunk = logical_chunk ^ (row & 7); staging uses the same map.
__device__ __forceinline__ bf16x8 ldsfrag(const u16* base, int row, int c8) {
  return *(const bf16x8*)(base + row * 64 + ((c8 ^ (row & 7)) << 3));
}

// DPP cross-lane (within 16-lane rows): VALU-pipe, avoids ds_swizzle latency.
template <int CTRL>
__device__ __forceinline__ float dppf(float x) {
  return __int_as_float(__builtin_amdgcn_update_dpp(0, __float_as_int(x), CTRL, 0xf, 0xf, true));
}
__device__ __forceinline__ float red16_max(float x) {
  x = fmaxf(x, dppf<0xB1>(x));   // xor 1 (quad_perm 1,0,3,2)
  x = fmaxf(x, dppf<0x4E>(x));   // xor 2 (quad_perm 2,3,0,1)
  x = fmaxf(x, dppf<0x141>(x));  // xor 4 (row_half_mirror)
  x = fmaxf(x, dppf<0x140>(x));  // xor 8 (row_mirror)
  return x;
}
__device__ __forceinline__ float red16_sum(float x) {
  x += dppf<0xB1>(x);
  x += dppf<0x4E>(x);
  x += dppf<0x141>(x);
  x += dppf<0x140>(x);
  return x;
}

// ---------------- fp32 -> bf16 convert (x) ----------------
__global__ __launch_bounds__(256) void k_cvt(const float* __restrict__ s, u16* __restrict__ d) {
  int i = (blockIdx.x * 256 + threadIdx.x) * 8;
  const float4* p = (const float4*)(s + i);
  float4 a = p[0], b = p[1];
  uint4 o;
  o.x = (u32)f2bf(a.x) | ((u32)f2bf(a.y) << 16);
  o.y = (u32)f2bf(a.z) | ((u32)f2bf(a.w) << 16);
  o.z = (u32)f2bf(b.x) | ((u32)f2bf(b.y) << 16);
  o.w = (u32)f2bf(b.z) | ((u32)f2bf(b.w) << 16);
  *(uint4*)(d + i) = o;
}

// ---------------- fp32 [rows][cols] -> bf16 transposed [cols][rows] ----------------
__global__ __launch_bounds__(256) void k_tr(const float* __restrict__ s, u16* __restrict__ d,
                                            int rows, int cols) {
  __shared__ float t[64][65];
  int c0 = blockIdx.x * 64, r0 = blockIdx.y * 64;
  int tx = threadIdx.x & 63, ty = threadIdx.x >> 6;
#pragma unroll
  for (int i = ty; i < 64; i += 4)
    t[i][tx] = s[(size_t)(r0 + i) * cols + c0 + tx];
  __syncthreads();
#pragma unroll
  for (int i = ty; i < 64; i += 4)
    d[(size_t)(c0 + i) * rows + r0 + tx] = f2bf(t[tx][i]);
}

// ---------------- shared 128x128x(K) bf16 MFMA GEMM core ----------------
__device__ __forceinline__ void gemm_core(const u16* __restrict__ A, const u16* __restrict__ Bt,
                                          const int K, const int m0, const int n0,
                                          u16* sA, u16* sB, f32x4 acc[4][4]) {
  const int tid = threadIdx.x;
  const int lane = tid & 63, w = tid >> 6;
  const int wm = (w >> 1) << 6, wn = (w & 1) << 6;
  const int lr = lane & 15, lq = lane >> 4;
  const int srow = tid >> 3;
  const int gcol = ((tid & 7) ^ (srow & 7)) << 3;
  const u16* ag = A + (size_t)(m0 + srow) * K + gcol;
  const u16* bg = Bt + (size_t)(n0 + srow) * K + gcol;
  u16* la = sA + w * 512;
  u16* lb = sB + w * 512;

  for (int k0 = 0; k0 < K; k0 += 64) {
    __syncthreads();
#pragma unroll
    for (int r = 0; r < 4; ++r) {
      gld_lds16(ag + (size_t)r * 32 * K + k0, la + r * 2048);
      gld_lds16(bg + (size_t)r * 32 * K + k0, lb + r * 2048);
    }
    __syncthreads();
#pragma unroll
    for (int kk = 0; kk < 64; kk += 32) {
      const int c8 = (kk >> 3) + lq;
      bf16x8 af[4], bfr[4];
#pragma unroll
      for (int i = 0; i < 4; ++i) {
        af[i] = ldsfrag(sA, wm + i * 16 + lr, c8);
        bfr[i] = ldsfrag(sB, wn + i * 16 + lr, c8);
      }
#pragma unroll
      for (int mi = 0; mi < 4; ++mi)
#pragma unroll
        for (int ni = 0; ni < 4; ++ni)
          acc[mi][ni] = __builtin_amdgcn_mfma_f32_16x16x32_bf16(af[mi], bfr[ni], acc[mi][ni], 0, 0, 0);
    }
  }
}

// ---------------- GEMM1: qkv = x @ W_attn + b, scattered to q/k/vt head layouts ----------------
__global__ __launch_bounds__(256) void k_gemm_qkv(const u16* __restrict__ xb,
                                                  const u16* __restrict__ Wt,
                                                  const float* __restrict__ bias,
                                                  u16* __restrict__ qb, u16* __restrict__ kb,
                                                  u16* __restrict__ vtb) {
  __shared__ u16 sA[128 * 64], sB[128 * 64];
  f32x4 acc[4][4];
#pragma unroll
  for (int mi = 0; mi < 4; ++mi)
#pragma unroll
    for (int ni = 0; ni < 4; ++ni) acc[mi][ni] = (f32x4){0.f, 0.f, 0.f, 0.f};
  const int m0 = blockIdx.y * 128, n0 = blockIdx.x * 128;
  gemm_core(xb, Wt, 1024, m0, n0, sA, sB, acc);

  const int lane = threadIdx.x & 63, w = threadIdx.x >> 6;
  const int wm = (w >> 1) << 6, wn = (w & 1) << 6, lr = lane & 15, lq = lane >> 4;
#pragma unroll
  for (int mi = 0; mi < 4; ++mi) {
    int gm = m0 + wm + mi * 16 + lq * 4;
#pragma unroll
    for (int ni = 0; ni < 4; ++ni) {
      int gn = n0 + wn + ni * 16 + lr;
      float bv = bias[gn];
      int which = gn >> 10, head = (gn >> 6) & 15, hd = gn & 63;
#pragma unroll
      for (int r = 0; r < 4; ++r) {
        int row = gm + r;
        int b = row >> 11, t = row & 2047;
        float v = acc[mi][ni][r] + bv;
        size_t bh = (size_t)(b * 16 + head);
        if (which == 0)
          qb[(bh * 2048 + t) * 64 + hd] = f2bf(v * 0.125f);  // fold 1/sqrt(64)
        else if (which == 1)
          kb[(bh * 2048 + t) * 64 + hd] = f2bf(v);
        else
          vtb[(bh * 64 + hd) * 2048 + t] = f2bf(v);  // V head-transposed [hd][T]
      }
    }
  }
}

// ---------------- flash attention v2: BQ=128, 8 waves x 16 rows, BKV=64 dbuf ----------------
__global__ __launch_bounds__(512, 4) void k_attn(const u16* __restrict__ qb,
                                                 const u16* __restrict__ kb,
                                                 const u16* __restrict__ vtb,
                                                 u16* __restrict__ yb) {
  __shared__ u16 sQ[128 * 64];     // 16KB
  __shared__ u16 sK[2][64 * 64];   // 16KB (double-buffered)
  __shared__ u16 sV[2][64 * 64];   // 16KB [hd][kv]
  __shared__ u16 sP[128 * 64];     // 16KB, XOR-swizzled (no pad -> 64KB total)

  const int tid = threadIdx.x;
  const int lane = tid & 63, w = tid >> 6;  // w in 0..7
  const int lr = lane & 15, lq = lane >> 4;
  const int bh = blockIdx.y;
  const int qt = 15 - blockIdx.x;  // heavy tiles first
  const int q0 = qt << 7;

  const u16* qh = qb + (size_t)bh * (2048 * 64);
  const u16* kh = kb + (size_t)bh * (2048 * 64);
  const u16* vh = vtb + (size_t)bh * (64 * 2048);

  const int srow = tid >> 3;                       // 0..63
  const int gcol = ((tid & 7) ^ (srow & 7)) << 3;  // swizzled 16B chunk

  {  // Q tile 128x64: 2 rounds of 64 rows
    u16* lqs = sQ + w * 512;
    const u16* gq = qh + (size_t)(q0 + srow) * 64 + gcol;
    gld_lds16(gq, lqs);
    gld_lds16(gq + 64 * 64, lqs + 4096);
  }
  // prefetch KV tile 0 into buf 0
  {
    gld_lds16(kh + (size_t)srow * 64 + gcol, sK[0] + w * 512);
    gld_lds16(vh + (size_t)srow * 2048 + gcol, sV[0] + w * 512);
  }

  f32x4 o[4];
  float mrow[4], lrow[4];
#pragma unroll
  for (int j = 0; j < 4; ++j) {
    o[j] = (f32x4){0.f, 0.f, 0.f, 0.f};
    mrow[j] = -1e30f;
    lrow[j] = 0.f;
  }

  const int ntiles = qt * 2 + 2;
  for (int it = 0; it < ntiles; ++it) {
    const int kv0 = it << 6;
    __syncthreads();  // publishes buf[it&1] (vmcnt drain had full prior compute in flight)
    if (it + 1 < ntiles) {  // prefetch next tile into the other buffer
      const int nkv = (it + 1) << 6;
      const int nb = (it + 1) & 1;
      gld_lds16(kh + (size_t)(nkv + srow) * 64 + gcol, sK[nb] + w * 512);
      gld_lds16(vh + (size_t)srow * 2048 + nkv + gcol, sV[nb] + w * 512);
    }
    const u16* cK = sK[it & 1];
    const u16* cV = sV[it & 1];

    // S = Q K^T : wave owns 16 q rows x 64 kv cols
    f32x4 s[4];
#pragma unroll
    for (int nj = 0; nj < 4; ++nj) s[nj] = (f32x4){0.f, 0.f, 0.f, 0.f};
#pragma unroll
    for (int kk = 0; kk < 64; kk += 32) {
      const int c8 = (kk >> 3) + lq;
      bf16x8 qa = ldsfrag(sQ, w * 16 + lr, c8);
      bf16x8 kf[4];
#pragma unroll
      for (int nj = 0; nj < 4; ++nj) kf[nj] = ldsfrag(cK, nj * 16 + lr, c8);
#pragma unroll
      for (int nj = 0; nj < 4; ++nj)
        s[nj] = __builtin_amdgcn_mfma_f32_16x16x32_bf16(qa, kf[nj], s[nj], 0, 0, 0);
    }

    if (kv0 + 64 > q0) {  // causal mask (diagonal tiles only)
      int qrow = q0 + w * 16 + lq * 4;
#pragma unroll
      for (int nj = 0; nj < 4; ++nj) {
        int col = kv0 + nj * 16 + lr;
#pragma unroll
        for (int r = 0; r < 4; ++r)
          if (col > qrow + r) s[nj][r] = -1e30f;
      }
    }

    // online softmax (C layout: row = lq*4+r over 16 lanes lr)
    float al[4];
#pragma unroll
    for (int r = 0; r < 4; ++r) {
      float mx = fmaxf(fmaxf(s[0][r], s[1][r]), fmaxf(s[2][r], s[3][r]));
      mx = red16_max(mx);
      float mn = fmaxf(mrow[r], mx);
      al[r] = __expf(mrow[r] - mn);
      mrow[r] = mn;
    }
#pragma unroll
    for (int nj = 0; nj < 4; ++nj)
#pragma unroll
      for (int r = 0; r < 4; ++r) o[nj][r] *= al[r];
    float rs[4];
#pragma unroll
    for (int r = 0; r < 4; ++r) rs[r] = 0.f;
#pragma unroll
    for (int nj = 0; nj < 4; ++nj)
#pragma unroll
      for (int r = 0; r < 4; ++r) {
        float p = __expf(s[nj][r] - mrow[r]);
        s[nj][r] = p;
        rs[r] += p;
      }
#pragma unroll
    for (int r = 0; r < 4; ++r) lrow[r] = lrow[r] * al[r] + red16_sum(rs[r]);

    // P -> sP (own wave's 16 rows; XOR-swizzled chunks, intra-wave only)
#pragma unroll
    for (int nj = 0; nj < 4; ++nj) {
      int chunk = nj * 2 + (lr >> 3);
#pragma unroll
      for (int r = 0; r < 4; ++r) {
        int row = w * 16 + lq * 4 + r;
        sP[row * 64 + ((chunk ^ (row & 7)) << 3) + (lr & 7)] = f2bf(s[nj][r]);
      }
    }
    asm volatile("s_waitcnt lgkmcnt(0)" ::: "memory");

    // O += P V
#pragma unroll
    for (int kk = 0; kk < 64; kk += 32) {
      const int c8 = (kk >> 3) + lq;
      bf16x8 pa = ldsfrag(sP, w * 16 + lr, c8);
      bf16x8 vf[4];
#pragma unroll
      for (int nj = 0; nj < 4; ++nj) vf[nj] = ldsfrag(cV, nj * 16 + lr, c8);
#pragma unroll
      for (int nj = 0; nj < 4; ++nj)
        o[nj] = __builtin_amdgcn_mfma_f32_16x16x32_bf16(pa, vf[nj], o[nj], 0, 0, 0);
    }
  }

  // y[b][t][h*64+hd] bf16
  const int b = bh >> 4, h = bh & 15;
#pragma unroll
  for (int r = 0; r < 4; ++r) {
    float inv = 1.0f / lrow[r];
    int row = q0 + w * 16 + lq * 4 + r;
    size_t base = ((size_t)(b * 2048 + row)) * 1024 + h * 64;
#pragma unroll
    for (int nj = 0; nj < 4; ++nj) yb[base + nj * 16 + lr] = f2bf(o[nj][r] * inv);
  }
}

// ---------------- GEMM2: out = y @ W_proj + b (fp32 out) ----------------
__global__ __launch_bounds__(256) void k_gemm_proj(const u16* __restrict__ ybuf,
                                                   const u16* __restrict__ Wt,
                                                   const float* __restrict__ bias,
                                                   float* __restrict__ out) {
  __shared__ u16 sA[128 * 64], sB[128 * 64];
  f32x4 acc[4][4];
#pragma unroll
  for (int mi = 0; mi < 4; ++mi)
#pragma unroll
    for (int ni = 0; ni < 4; ++ni) acc[mi][ni] = (f32x4){0.f, 0.f, 0.f, 0.f};
  const int m0 = blockIdx.y * 128, n0 = blockIdx.x * 128;
  gemm_core(ybuf, Wt, 1024, m0, n0, sA, sB, acc);

  const int lane = threadIdx.x & 63, w = threadIdx.x >> 6;
  const int wm = (w >> 1) << 6, wn = (w & 1) << 6, lr = lane & 15, lq = lane >> 4;
#pragma unroll
  for (int mi = 0; mi < 4; ++mi) {
    int gm = m0 + wm + mi * 16 + lq * 4;
#pragma unroll
    for (int ni = 0; ni < 4; ++ni) {
      int gn = n0 + wn + ni * 16 + lr;
      float bv = bias[gn];
#pragma unroll
      for (int r = 0; r < 4; ++r) out[(size_t)(gm + r) * 1024 + gn] = acc[mi][ni][r] + bv;
    }
  }
}

extern "C" void kernel_launch(void* const* d_in, const int* in_sizes, int n_in,
                              void* d_out, int out_size, void* d_ws, size_t ws_size,
                              hipStream_t stream) {
  const float* x = (const float*)d_in[0];       // [2,2048,1024]
  const float* W_attn = (const float*)d_in[1];  // [1024,3072]
  const float* b_attn = (const float*)d_in[2];  // [3072]
  const float* W_proj = (const float*)d_in[3];  // [1024,1024]
  const float* b_proj = (const float*)d_in[4];  // [1024]
  float* out = (float*)d_out;                   // [2,2048,1024] fp32

  u16* ws = (u16*)d_ws;
  u16* xb = ws;                   // 4096x1024 bf16
  u16* WaT = ws + 4194304;        // 3072x1024 (W_attn^T)
  u16* WpT = ws + 7340032;        // 1024x1024 (W_proj^T)
  u16* qbuf = ws + 8388608;       // [32][2048][64]
  u16* kbuf = ws + 12582912;      // [32][2048][64]
  u16* vtb = ws + 16777216;       // [32][64][2048]
  u16* ybuf = ws + 20971520;      // [4096][1024]

  k_cvt<<<dim3(2048), dim3(256), 0, stream>>>(x, xb);
  k_tr<<<dim3(48, 16), dim3(256), 0, stream>>>(W_attn, WaT, 1024, 3072);
  k_tr<<<dim3(16, 16), dim3(256), 0, stream>>>(W_proj, WpT, 1024, 1024);
  k_gemm_qkv<<<dim3(24, 32), dim3(256), 0, stream>>>(xb, WaT, b_attn, qbuf, kbuf, vtb);
  k_attn<<<dim3(16, 32), dim3(512), 0, stream>>>(qbuf, kbuf, vtb, ybuf);
  k_gemm_proj<<<dim3(8, 32), dim3(256), 0, stream>>>(ybuf, WpT, b_proj, out);
}

// Round 3
// 228.630 us; speedup vs baseline: 1.1992x; 1.0834x over previous
//
#include <hip/hip_runtime.h>

typedef unsigned short u16;
typedef unsigned int u32;
typedef short bf16x8 __attribute__((ext_vector_type(8)));
typedef float f32x4 __attribute__((ext_vector_type(4)));

__device__ __forceinline__ u16 f2bf(float f) {
  union { float f; u32 u; } v; v.f = f;
  u32 r = v.u + 0x7fffu + ((v.u >> 16) & 1u);
  return (u16)(r >> 16);
}

__device__ __forceinline__ void gld_lds16(const u16* g, u16* l) {
  __builtin_amdgcn_global_load_lds(
      (__attribute__((address_space(1))) u32*)(g),
      (__attribute__((address_space(3))) u32*)(l),
      16, 0, 0);
}

// LDS fragment read with XOR-16B swizzle (rows of 64 bf16 = 8 chunks of 16B).
// Physical chunk = logical_chunk ^ (row & 7); staging uses the same map.
__device__ __forceinline__ bf16x8 ldsfrag(const u16* base, int row, int c8) {
  return *(const bf16x8*)(base + row * 64 + ((c8 ^ (row & 7)) << 3));
}

// DPP cross-lane (within 16-lane rows): VALU-pipe, avoids ds_swizzle latency.
template <int CTRL>
__device__ __forceinline__ float dppf(float x) {
  return __int_as_float(__builtin_amdgcn_update_dpp(0, __float_as_int(x), CTRL, 0xf, 0xf, true));
}
__device__ __forceinline__ float red16_max(float x) {
  x = fmaxf(x, dppf<0xB1>(x));   // xor 1
  x = fmaxf(x, dppf<0x4E>(x));   // xor 2
  x = fmaxf(x, dppf<0x141>(x));  // xor 4
  x = fmaxf(x, dppf<0x140>(x));  // xor 8
  return x;
}
__device__ __forceinline__ float red16_sum(float x) {
  x += dppf<0xB1>(x);
  x += dppf<0x4E>(x);
  x += dppf<0x141>(x);
  x += dppf<0x140>(x);
  return x;
}

// ---------------- fp32 -> bf16 convert (x) ----------------
__global__ __launch_bounds__(256) void k_cvt(const float* __restrict__ s, u16* __restrict__ d) {
  int i = (blockIdx.x * 256 + threadIdx.x) * 8;
  const float4* p = (const float4*)(s + i);
  float4 a = p[0], b = p[1];
  uint4 o;
  o.x = (u32)f2bf(a.x) | ((u32)f2bf(a.y) << 16);
  o.y = (u32)f2bf(a.z) | ((u32)f2bf(a.w) << 16);
  o.z = (u32)f2bf(b.x) | ((u32)f2bf(b.y) << 16);
  o.w = (u32)f2bf(b.z) | ((u32)f2bf(b.w) << 16);
  *(uint4*)(d + i) = o;
}

// ---------------- fp32 [rows][cols] -> bf16 transposed [cols][rows] ----------------
__global__ __launch_bounds__(256) void k_tr(const float* __restrict__ s, u16* __restrict__ d,
                                            int rows, int cols) {
  __shared__ float t[64][65];
  int c0 = blockIdx.x * 64, r0 = blockIdx.y * 64;
  int tx = threadIdx.x & 63, ty = threadIdx.x >> 6;
#pragma unroll
  for (int i = ty; i < 64; i += 4)
    t[i][tx] = s[(size_t)(r0 + i) * cols + c0 + tx];
  __syncthreads();
#pragma unroll
  for (int i = ty; i < 64; i += 4)
    d[(size_t)(c0 + i) * rows + r0 + tx] = f2bf(t[tx][i]);
}

// ---------------- shared 128x128x(K) bf16 MFMA GEMM core ----------------
__device__ __forceinline__ void gemm_core(const u16* __restrict__ A, const u16* __restrict__ Bt,
                                          const int K, const int m0, const int n0,
                                          u16* sA, u16* sB, f32x4 acc[4][4]) {
  const int tid = threadIdx.x;
  const int lane = tid & 63, w = tid >> 6;
  const int wm = (w >> 1) << 6, wn = (w & 1) << 6;
  const int lr = lane & 15, lq = lane >> 4;
  const int srow = tid >> 3;
  const int gcol = ((tid & 7) ^ (srow & 7)) << 3;
  const u16* ag = A + (size_t)(m0 + srow) * K + gcol;
  const u16* bg = Bt + (size_t)(n0 + srow) * K + gcol;
  u16* la = sA + w * 512;
  u16* lb = sB + w * 512;

  for (int k0 = 0; k0 < K; k0 += 64) {
    __syncthreads();
#pragma unroll
    for (int r = 0; r < 4; ++r) {
      gld_lds16(ag + (size_t)r * 32 * K + k0, la + r * 2048);
      gld_lds16(bg + (size_t)r * 32 * K + k0, lb + r * 2048);
    }
    __syncthreads();
#pragma unroll
    for (int kk = 0; kk < 64; kk += 32) {
      const int c8 = (kk >> 3) + lq;
      bf16x8 af[4], bfr[4];
#pragma unroll
      for (int i = 0; i < 4; ++i) {
        af[i] = ldsfrag(sA, wm + i * 16 + lr, c8);
        bfr[i] = ldsfrag(sB, wn + i * 16 + lr, c8);
      }
#pragma unroll
      for (int mi = 0; mi < 4; ++mi)
#pragma unroll
        for (int ni = 0; ni < 4; ++ni)
          acc[mi][ni] = __builtin_amdgcn_mfma_f32_16x16x32_bf16(af[mi], bfr[ni], acc[mi][ni], 0, 0, 0);
    }
  }
}

// ---------------- GEMM1: qkv = x @ W_attn + b, scattered to q/k/vt head layouts ----------------
__global__ __launch_bounds__(256) void k_gemm_qkv(const u16* __restrict__ xb,
                                                  const u16* __restrict__ Wt,
                                                  const float* __restrict__ bias,
                                                  u16* __restrict__ qb, u16* __restrict__ kb,
                                                  u16* __restrict__ vtb) {
  __shared__ u16 sA[128 * 64], sB[128 * 64];
  f32x4 acc[4][4];
#pragma unroll
  for (int mi = 0; mi < 4; ++mi)
#pragma unroll
    for (int ni = 0; ni < 4; ++ni) acc[mi][ni] = (f32x4){0.f, 0.f, 0.f, 0.f};
  const int m0 = blockIdx.y * 128, n0 = blockIdx.x * 128;
  gemm_core(xb, Wt, 1024, m0, n0, sA, sB, acc);

  const int lane = threadIdx.x & 63, w = threadIdx.x >> 6;
  const int wm = (w >> 1) << 6, wn = (w & 1) << 6, lr = lane & 15, lq = lane >> 4;
#pragma unroll
  for (int mi = 0; mi < 4; ++mi) {
    int gm = m0 + wm + mi * 16 + lq * 4;
#pragma unroll
    for (int ni = 0; ni < 4; ++ni) {
      int gn = n0 + wn + ni * 16 + lr;
      float bv = bias[gn];
      int which = gn >> 10, head = (gn >> 6) & 15, hd = gn & 63;
#pragma unroll
      for (int r = 0; r < 4; ++r) {
        int row = gm + r;
        int b = row >> 11, t = row & 2047;
        float v = acc[mi][ni][r] + bv;
        size_t bh = (size_t)(b * 16 + head);
        if (which == 0)
          qb[(bh * 2048 + t) * 64 + hd] = f2bf(v * 0.125f);  // fold 1/sqrt(64)
        else if (which == 1)
          kb[(bh * 2048 + t) * 64 + hd] = f2bf(v);
        else
          vtb[(bh * 64 + hd) * 2048 + t] = f2bf(v);  // V head-transposed [hd][T]
      }
    }
  }
}

// ---------------- flash attention v3: complementary q-tile pairs per block ----------------
// Grid (8, 32): block x handles q-tiles {15-x, x} -> every block runs exactly 34
// kv-tile iterations (perfect static balance; fixes the round-2 CU imbalance where
// blockIdx.x aliased mod-256 dispatch gave some CUs 64 iters and others 4).
__global__ __launch_bounds__(512, 4) void k_attn(const u16* __restrict__ qb,
                                                 const u16* __restrict__ kb,
                                                 const u16* __restrict__ vtb,
                                                 u16* __restrict__ yb) {
  __shared__ u16 sQ[128 * 64];     // 16KB
  __shared__ u16 sK[2][64 * 64];   // 16KB (double-buffered)
  __shared__ u16 sV[2][64 * 64];   // 16KB [hd][kv]
  __shared__ u16 sP[128 * 64];     // 16KB, XOR-swizzled

  const int tid = threadIdx.x;
  const int lane = tid & 63, w = tid >> 6;  // w in 0..7
  const int lr = lane & 15, lq = lane >> 4;
  const int bh = blockIdx.y;

  const u16* qh = qb + (size_t)bh * (2048 * 64);
  const u16* kh = kb + (size_t)bh * (2048 * 64);
  const u16* vh = vtb + (size_t)bh * (64 * 2048);

  const int srow = tid >> 3;                       // 0..63
  const int gcol = ((tid & 7) ^ (srow & 7)) << 3;  // swizzled 16B chunk

  const int b = bh >> 4, h = bh & 15;

  for (int phase = 0; phase < 2; ++phase) {
    const int qt = phase ? blockIdx.x : (15 - blockIdx.x);
    const int q0 = qt << 7;

    __syncthreads();  // prior phase's sQ/sK/sV reads complete before restaging

    {  // Q tile 128x64: 2 rounds of 64 rows
      u16* lqs = sQ + w * 512;
      const u16* gq = qh + (size_t)(q0 + srow) * 64 + gcol;
      gld_lds16(gq, lqs);
      gld_lds16(gq + 64 * 64, lqs + 4096);
    }
    // prefetch KV tile 0 into buf 0
    gld_lds16(kh + (size_t)srow * 64 + gcol, sK[0] + w * 512);
    gld_lds16(vh + (size_t)srow * 2048 + gcol, sV[0] + w * 512);

    f32x4 o[4];
    float mrow[4], lrow[4];
#pragma unroll
    for (int j = 0; j < 4; ++j) {
      o[j] = (f32x4){0.f, 0.f, 0.f, 0.f};
      mrow[j] = -1e30f;
      lrow[j] = 0.f;
    }

    const int ntiles = qt * 2 + 2;
    for (int it = 0; it < ntiles; ++it) {
      const int kv0 = it << 6;
      __syncthreads();  // publishes buf[it&1]
      if (it + 1 < ntiles) {  // prefetch next tile into the other buffer
        const int nkv = (it + 1) << 6;
        const int nb = (it + 1) & 1;
        gld_lds16(kh + (size_t)(nkv + srow) * 64 + gcol, sK[nb] + w * 512);
        gld_lds16(vh + (size_t)srow * 2048 + nkv + gcol, sV[nb] + w * 512);
      }
      const u16* cK = sK[it & 1];
      const u16* cV = sV[it & 1];

      // S = Q K^T : wave owns 16 q rows x 64 kv cols
      f32x4 s[4];
#pragma unroll
      for (int nj = 0; nj < 4; ++nj) s[nj] = (f32x4){0.f, 0.f, 0.f, 0.f};
#pragma unroll
      for (int kk = 0; kk < 64; kk += 32) {
        const int c8 = (kk >> 3) + lq;
        bf16x8 qa = ldsfrag(sQ, w * 16 + lr, c8);
        bf16x8 kf[4];
#pragma unroll
        for (int nj = 0; nj < 4; ++nj) kf[nj] = ldsfrag(cK, nj * 16 + lr, c8);
#pragma unroll
        for (int nj = 0; nj < 4; ++nj)
          s[nj] = __builtin_amdgcn_mfma_f32_16x16x32_bf16(qa, kf[nj], s[nj], 0, 0, 0);
      }

      if (kv0 + 64 > q0) {  // causal mask (diagonal tiles only)
        int qrow = q0 + w * 16 + lq * 4;
#pragma unroll
        for (int nj = 0; nj < 4; ++nj) {
          int col = kv0 + nj * 16 + lr;
#pragma unroll
          for (int r = 0; r < 4; ++r)
            if (col > qrow + r) s[nj][r] = -1e30f;
        }
      }

      // online softmax (C layout: row = lq*4+r over 16 lanes lr)
      float al[4];
#pragma unroll
      for (int r = 0; r < 4; ++r) {
        float mx = fmaxf(fmaxf(s[0][r], s[1][r]), fmaxf(s[2][r], s[3][r]));
        mx = red16_max(mx);
        float mn = fmaxf(mrow[r], mx);
        al[r] = __expf(mrow[r] - mn);
        mrow[r] = mn;
      }
#pragma unroll
      for (int nj = 0; nj < 4; ++nj)
#pragma unroll
        for (int r = 0; r < 4; ++r) o[nj][r] *= al[r];
      float rs[4];
#pragma unroll
      for (int r = 0; r < 4; ++r) rs[r] = 0.f;
#pragma unroll
      for (int nj = 0; nj < 4; ++nj)
#pragma unroll
        for (int r = 0; r < 4; ++r) {
          float p = __expf(s[nj][r] - mrow[r]);
          s[nj][r] = p;
          rs[r] += p;
        }
#pragma unroll
      for (int r = 0; r < 4; ++r) lrow[r] = lrow[r] * al[r] + red16_sum(rs[r]);

      // P -> sP (own wave's 16 rows; XOR-swizzled chunks, intra-wave only)
#pragma unroll
      for (int nj = 0; nj < 4; ++nj) {
        int chunk = nj * 2 + (lr >> 3);
#pragma unroll
        for (int r = 0; r < 4; ++r) {
          int row = w * 16 + lq * 4 + r;
          sP[row * 64 + ((chunk ^ (row & 7)) << 3) + (lr & 7)] = f2bf(s[nj][r]);
        }
      }
      asm volatile("s_waitcnt lgkmcnt(0)" ::: "memory");

      // O += P V
#pragma unroll
      for (int kk = 0; kk < 64; kk += 32) {
        const int c8 = (kk >> 3) + lq;
        bf16x8 pa = ldsfrag(sP, w * 16 + lr, c8);
        bf16x8 vf[4];
#pragma unroll
        for (int nj = 0; nj < 4; ++nj) vf[nj] = ldsfrag(cV, nj * 16 + lr, c8);
#pragma unroll
        for (int nj = 0; nj < 4; ++nj)
          o[nj] = __builtin_amdgcn_mfma_f32_16x16x32_bf16(pa, vf[nj], o[nj], 0, 0, 0);
      }
    }

    // y[b][t][h*64+hd] bf16
#pragma unroll
    for (int r = 0; r < 4; ++r) {
      float inv = 1.0f / lrow[r];
      int row = q0 + w * 16 + lq * 4 + r;
      size_t base = ((size_t)(b * 2048 + row)) * 1024 + h * 64;
#pragma unroll
      for (int nj = 0; nj < 4; ++nj) yb[base + nj * 16 + lr] = f2bf(o[nj][r] * inv);
    }
  }
}

// ---------------- GEMM2: out = y @ W_proj + b (fp32 out) ----------------
__global__ __launch_bounds__(256) void k_gemm_proj(const u16* __restrict__ ybuf,
                                                   const u16* __restrict__ Wt,
                                                   const float* __restrict__ bias,
                                                   float* __restrict__ out) {
  __shared__ u16 sA[128 * 64], sB[128 * 64];
  f32x4 acc[4][4];
#pragma unroll
  for (int mi = 0; mi < 4; ++mi)
#pragma unroll
    for (int ni = 0; ni < 4; ++ni) acc[mi][ni] = (f32x4){0.f, 0.f, 0.f, 0.f};
  const int m0 = blockIdx.y * 128, n0 = blockIdx.x * 128;
  gemm_core(ybuf, Wt, 1024, m0, n0, sA, sB, acc);

  const int lane = threadIdx.x & 63, w = threadIdx.x >> 6;
  const int wm = (w >> 1) << 6, wn = (w & 1) << 6, lr = lane & 15, lq = lane >> 4;
#pragma unroll
  for (int mi = 0; mi < 4; ++mi) {
    int gm = m0 + wm + mi * 16 + lq * 4;
#pragma unroll
    for (int ni = 0; ni < 4; ++ni) {
      int gn = n0 + wn + ni * 16 + lr;
      float bv = bias[gn];
#pragma unroll
      for (int r = 0; r < 4; ++r) out[(size_t)(gm + r) * 1024 + gn] = acc[mi][ni][r] + bv;
    }
  }
}

extern "C" void kernel_launch(void* const* d_in, const int* in_sizes, int n_in,
                              void* d_out, int out_size, void* d_ws, size_t ws_size,
                              hipStream_t stream) {
  const float* x = (const float*)d_in[0];       // [2,2048,1024]
  const float* W_attn = (const float*)d_in[1];  // [1024,3072]
  const float* b_attn = (const float*)d_in[2];  // [3072]
  const float* W_proj = (const float*)d_in[3];  // [1024,1024]
  const float* b_proj = (const float*)d_in[4];  // [1024]
  float* out = (float*)d_out;                   // [2,2048,1024] fp32

  u16* ws = (u16*)d_ws;
  u16* xb = ws;                   // 4096x1024 bf16
  u16* WaT = ws + 4194304;        // 3072x1024 (W_attn^T)
  u16* WpT = ws + 7340032;        // 1024x1024 (W_proj^T)
  u16* qbuf = ws + 8388608;       // [32][2048][64]
  u16* kbuf = ws + 12582912;      // [32][2048][64]
  u16* vtb = ws + 16777216;       // [32][64][2048]
  u16* ybuf = ws + 20971520;      // [4096][1024]

  k_cvt<<<dim3(2048), dim3(256), 0, stream>>>(x, xb);
  k_tr<<<dim3(48, 16), dim3(256), 0, stream>>>(W_attn, WaT, 1024, 3072);
  k_tr<<<dim3(16, 16), dim3(256), 0, stream>>>(W_proj, WpT, 1024, 1024);
  k_gemm_qkv<<<dim3(24, 32), dim3(256), 0, stream>>>(xb, WaT, b_attn, qbuf, kbuf, vtb);
  k_attn<<<dim3(8, 32), dim3(512), 0, stream>>>(qbuf, kbuf, vtb, ybuf);
  k_gemm_proj<<<dim3(8, 32), dim3(256), 0, stream>>>(ybuf, WpT, b_proj, out);
}

// Round 4
// 227.336 us; speedup vs baseline: 1.2060x; 1.0057x over previous
//
#include <hip/hip_runtime.h>

typedef unsigned short u16;
typedef unsigned int u32;
typedef short bf16x8 __attribute__((ext_vector_type(8)));
typedef float f32x4 __attribute__((ext_vector_type(4)));

__device__ __forceinline__ u16 f2bf(float f) {
  union { float f; u32 u; } v; v.f = f;
  u32 r = v.u + 0x7fffu + ((v.u >> 16) & 1u);
  return (u16)(r >> 16);
}
// cheap round-half-up (P matrix only; values in [0,1], bias negligible)
__device__ __forceinline__ u16 f2bf_fast(float f) {
  union { float f; u32 u; } v; v.f = f;
  return (u16)((v.u + 0x8000u) >> 16);
}
__device__ __forceinline__ float fexp2(float x) {
#if __has_builtin(__builtin_amdgcn_exp2f)
  return __builtin_amdgcn_exp2f(x);
#else
  return exp2f(x);
#endif
}

__device__ __forceinline__ void gld_lds16(const u16* g, u16* l) {
  __builtin_amdgcn_global_load_lds(
      (__attribute__((address_space(1))) u32*)(g),
      (__attribute__((address_space(3))) u32*)(l),
      16, 0, 0);
}

// LDS fragment read with XOR-16B swizzle (rows of 64 bf16 = 8 chunks of 16B).
__device__ __forceinline__ bf16x8 ldsfrag(const u16* base, int row, int c8) {
  return *(const bf16x8*)(base + row * 64 + ((c8 ^ (row & 7)) << 3));
}

// DPP cross-lane (within 16-lane rows): VALU-pipe reduction.
template <int CTRL>
__device__ __forceinline__ float dppf(float x) {
  return __int_as_float(__builtin_amdgcn_update_dpp(0, __float_as_int(x), CTRL, 0xf, 0xf, true));
}
__device__ __forceinline__ float red16_max(float x) {
  x = fmaxf(x, dppf<0xB1>(x));
  x = fmaxf(x, dppf<0x4E>(x));
  x = fmaxf(x, dppf<0x141>(x));
  x = fmaxf(x, dppf<0x140>(x));
  return x;
}
__device__ __forceinline__ float red16_sum(float x) {
  x += dppf<0xB1>(x);
  x += dppf<0x4E>(x);
  x += dppf<0x141>(x);
  x += dppf<0x140>(x);
  return x;
}

// ---------------- fp32 -> bf16 convert (x) ----------------
__global__ __launch_bounds__(256) void k_cvt(const float* __restrict__ s, u16* __restrict__ d) {
  int i = (blockIdx.x * 256 + threadIdx.x) * 8;
  const float4* p = (const float4*)(s + i);
  float4 a = p[0], b = p[1];
  uint4 o;
  o.x = (u32)f2bf(a.x) | ((u32)f2bf(a.y) << 16);
  o.y = (u32)f2bf(a.z) | ((u32)f2bf(a.w) << 16);
  o.z = (u32)f2bf(b.x) | ((u32)f2bf(b.y) << 16);
  o.w = (u32)f2bf(b.z) | ((u32)f2bf(b.w) << 16);
  *(uint4*)(d + i) = o;
}

// ---------------- fp32 [rows][cols] -> bf16 transposed [cols][rows] ----------------
__global__ __launch_bounds__(256) void k_tr(const float* __restrict__ s, u16* __restrict__ d,
                                            int rows, int cols) {
  __shared__ float t[64][65];
  int c0 = blockIdx.x * 64, r0 = blockIdx.y * 64;
  int tx = threadIdx.x & 63, ty = threadIdx.x >> 6;
#pragma unroll
  for (int i = ty; i < 64; i += 4)
    t[i][tx] = s[(size_t)(r0 + i) * cols + c0 + tx];
  __syncthreads();
#pragma unroll
  for (int i = ty; i < 64; i += 4)
    d[(size_t)(c0 + i) * rows + r0 + tx] = f2bf(t[tx][i]);
}

// ---------------- shared 128x128x(K) bf16 MFMA GEMM core ----------------
__device__ __forceinline__ void gemm_core(const u16* __restrict__ A, const u16* __restrict__ Bt,
                                          const int K, const int m0, const int n0,
                                          u16* sA, u16* sB, f32x4 acc[4][4]) {
  const int tid = threadIdx.x;
  const int lane = tid & 63, w = tid >> 6;
  const int wm = (w >> 1) << 6, wn = (w & 1) << 6;
  const int lr = lane & 15, lq = lane >> 4;
  const int srow = tid >> 3;
  const int gcol = ((tid & 7) ^ (srow & 7)) << 3;
  const u16* ag = A + (size_t)(m0 + srow) * K + gcol;
  const u16* bg = Bt + (size_t)(n0 + srow) * K + gcol;
  u16* la = sA + w * 512;
  u16* lb = sB + w * 512;

  for (int k0 = 0; k0 < K; k0 += 64) {
    __syncthreads();
#pragma unroll
    for (int r = 0; r < 4; ++r) {
      gld_lds16(ag + (size_t)r * 32 * K + k0, la + r * 2048);
      gld_lds16(bg + (size_t)r * 32 * K + k0, lb + r * 2048);
    }
    __syncthreads();
#pragma unroll
    for (int kk = 0; kk < 64; kk += 32) {
      const int c8 = (kk >> 3) + lq;
      bf16x8 af[4], bfr[4];
#pragma unroll
      for (int i = 0; i < 4; ++i) {
        af[i] = ldsfrag(sA, wm + i * 16 + lr, c8);
        bfr[i] = ldsfrag(sB, wn + i * 16 + lr, c8);
      }
#pragma unroll
      for (int mi = 0; mi < 4; ++mi)
#pragma unroll
        for (int ni = 0; ni < 4; ++ni)
          acc[mi][ni] = __builtin_amdgcn_mfma_f32_16x16x32_bf16(af[mi], bfr[ni], acc[mi][ni], 0, 0, 0);
    }
  }
}

// ---------------- GEMM1: qkv = x @ W_attn + b, scattered to q/k/vt head layouts ----------------
__global__ __launch_bounds__(256) void k_gemm_qkv(const u16* __restrict__ xb,
                                                  const u16* __restrict__ Wt,
                                                  const float* __restrict__ bias,
                                                  u16* __restrict__ qb, u16* __restrict__ kb,
                                                  u16* __restrict__ vtb) {
  __shared__ u16 sA[128 * 64], sB[128 * 64];
  f32x4 acc[4][4];
#pragma unroll
  for (int mi = 0; mi < 4; ++mi)
#pragma unroll
    for (int ni = 0; ni < 4; ++ni) acc[mi][ni] = (f32x4){0.f, 0.f, 0.f, 0.f};
  const int m0 = blockIdx.y * 128, n0 = blockIdx.x * 128;
  gemm_core(xb, Wt, 1024, m0, n0, sA, sB, acc);

  const int lane = threadIdx.x & 63, w = threadIdx.x >> 6;
  const int wm = (w >> 1) << 6, wn = (w & 1) << 6, lr = lane & 15, lq = lane >> 4;
#pragma unroll
  for (int mi = 0; mi < 4; ++mi) {
    int gm = m0 + wm + mi * 16 + lq * 4;
#pragma unroll
    for (int ni = 0; ni < 4; ++ni) {
      int gn = n0 + wn + ni * 16 + lr;
      float bv = bias[gn];
      int which = gn >> 10, head = (gn >> 6) & 15, hd = gn & 63;
#pragma unroll
      for (int r = 0; r < 4; ++r) {
        int row = gm + r;
        int b = row >> 11, t = row & 2047;
        float v = acc[mi][ni][r] + bv;
        size_t bh = (size_t)(b * 16 + head);
        if (which == 0)
          qb[(bh * 2048 + t) * 64 + hd] = f2bf(v * 0.125f);  // fold 1/sqrt(64)
        else if (which == 1)
          kb[(bh * 2048 + t) * 64 + hd] = f2bf(v);
        else
          vtb[(bh * 64 + hd) * 2048 + t] = f2bf(v);  // V head-transposed [hd][T]
      }
    }
  }
}

// ---------------- flash attention v4: 32-row waves, 2 blocks/CU ----------------
// 512 linear blocks; blocks l and l+256 decode to the same (bh,x) with
// complementary q-tiles (15-x vs x). Round-robin dispatch puts them on the SAME
// CU (round-2 evidence): per-CU work is a constant 36 tile-rounds, and the two
// co-resident blocks stream the same head's K/V (L2 reuse) while overlapping
// each other's barrier/softmax stalls. 32-row waves cut LDS fragment traffic
// from 20 B to 12 B per S-element.
__global__ __launch_bounds__(256, 2) void k_attn(const u16* __restrict__ qb,
                                                 const u16* __restrict__ kb,
                                                 const u16* __restrict__ vtb,
                                                 u16* __restrict__ yb) {
  __shared__ u16 sQ[128 * 64];    // 16KB
  __shared__ u16 sK[2][64 * 64];  // 16KB dbuf
  __shared__ u16 sV[2][64 * 64];  // 16KB dbuf, [hd][kv]
  __shared__ u16 sP[128 * 64];    // 16KB, XOR-swizzled  -> 64KB total, 2 blocks/CU

  const int tid = threadIdx.x;
  const int lane = tid & 63, w = tid >> 6;  // w in 0..3
  const int lr = lane & 15, lq = lane >> 4;
  const int l = blockIdx.x;
  const int x = l & 7, bh = (l & 255) >> 3;
  const int qt = (l >> 8) ? x : (15 - x);
  const int q0 = qt << 7;

  const u16* qh = qb + (size_t)bh * (2048 * 64);
  const u16* kh = kb + (size_t)bh * (2048 * 64);
  const u16* vh = vtb + (size_t)bh * (64 * 2048);

  const int srow = tid >> 3;                       // 0..31
  const int gcol = ((tid & 7) ^ (srow & 7)) << 3;  // swizzled 16B chunk

  {  // Q tile 128x64: 4 rounds of 32 rows
    u16* lqs = sQ + w * 512;
    const u16* gq = qh + (size_t)(q0 + srow) * 64 + gcol;
#pragma unroll
    for (int r = 0; r < 4; ++r) gld_lds16(gq + (size_t)(r * 32) * 64, lqs + r * 2048);
  }
  {  // KV tile 0 -> buf 0 (2 rounds of 32 rows each)
    u16* lk = sK[0] + w * 512;
    u16* lv = sV[0] + w * 512;
#pragma unroll
    for (int r = 0; r < 2; ++r) {
      gld_lds16(kh + (size_t)(r * 32 + srow) * 64 + gcol, lk + r * 2048);
      gld_lds16(vh + (size_t)(r * 32 + srow) * 2048 + gcol, lv + r * 2048);
    }
  }

  const float L2E = 1.44269504f;
  f32x4 o[2][4];
  float mL2[2][4], lrow[2][4];  // running max pre-scaled by log2e
#pragma unroll
  for (int mi = 0; mi < 2; ++mi)
#pragma unroll
    for (int j = 0; j < 4; ++j) {
      o[mi][j] = (f32x4){0.f, 0.f, 0.f, 0.f};
      mL2[mi][j] = -1e30f;
      lrow[mi][j] = 0.f;
    }

  const int ntiles = (qt << 1) + 2;
  for (int it = 0; it < ntiles; ++it) {
    const int kv0 = it << 6;
    __syncthreads();        // publishes buf[it&1]
    if (it + 1 < ntiles) {  // prefetch next tile into the other buffer
      const int nkv = (it + 1) << 6;
      const int nb = (it + 1) & 1;
      u16* lk = sK[nb] + w * 512;
      u16* lv = sV[nb] + w * 512;
#pragma unroll
      for (int r = 0; r < 2; ++r) {
        gld_lds16(kh + (size_t)(nkv + r * 32 + srow) * 64 + gcol, lk + r * 2048);
        gld_lds16(vh + (size_t)(r * 32 + srow) * 2048 + nkv + gcol, lv + r * 2048);
      }
    }
    const u16* cK = sK[it & 1];
    const u16* cV = sV[it & 1];

    // S = Q K^T : wave owns 32 q rows (mi=2) x 64 kv cols
    f32x4 s[2][4];
#pragma unroll
    for (int mi = 0; mi < 2; ++mi)
#pragma unroll
      for (int nj = 0; nj < 4; ++nj) s[mi][nj] = (f32x4){0.f, 0.f, 0.f, 0.f};
#pragma unroll
    for (int kk = 0; kk < 64; kk += 32) {
      const int c8 = (kk >> 3) + lq;
      bf16x8 qa[2], kf[4];
#pragma unroll
      for (int mi = 0; mi < 2; ++mi) qa[mi] = ldsfrag(sQ, w * 32 + mi * 16 + lr, c8);
#pragma unroll
      for (int nj = 0; nj < 4; ++nj) kf[nj] = ldsfrag(cK, nj * 16 + lr, c8);
#pragma unroll
      for (int mi = 0; mi < 2; ++mi)
#pragma unroll
        for (int nj = 0; nj < 4; ++nj)
          s[mi][nj] = __builtin_amdgcn_mfma_f32_16x16x32_bf16(qa[mi], kf[nj], s[mi][nj], 0, 0, 0);
    }

    if (kv0 + 64 > q0) {  // causal mask (diagonal region only)
#pragma unroll
      for (int mi = 0; mi < 2; ++mi) {
        int qrow = q0 + w * 32 + mi * 16 + lq * 4;
#pragma unroll
        for (int nj = 0; nj < 4; ++nj) {
          int col = kv0 + nj * 16 + lr;
#pragma unroll
          for (int r = 0; r < 4; ++r)
            if (col > qrow + r) s[mi][nj][r] = -1e30f;
        }
      }
    }

    // online softmax in exp2 domain
#pragma unroll
    for (int mi = 0; mi < 2; ++mi) {
      float al[4];
#pragma unroll
      for (int r = 0; r < 4; ++r) {
        float mx = fmaxf(fmaxf(s[mi][0][r], s[mi][1][r]), fmaxf(s[mi][2][r], s[mi][3][r]));
        mx = red16_max(mx) * L2E;
        float mn = fmaxf(mL2[mi][r], mx);
        al[r] = fexp2(mL2[mi][r] - mn);
        mL2[mi][r] = mn;
      }
#pragma unroll
      for (int nj = 0; nj < 4; ++nj)
#pragma unroll
        for (int r = 0; r < 4; ++r) o[mi][nj][r] *= al[r];
      float rs[4];
#pragma unroll
      for (int r = 0; r < 4; ++r) rs[r] = 0.f;
#pragma unroll
      for (int nj = 0; nj < 4; ++nj)
#pragma unroll
        for (int r = 0; r < 4; ++r) {
          float p = fexp2(fmaf(s[mi][nj][r], L2E, -mL2[mi][r]));
          s[mi][nj][r] = p;
          rs[r] += p;
        }
#pragma unroll
      for (int r = 0; r < 4; ++r) lrow[mi][r] = lrow[mi][r] * al[r] + red16_sum(rs[r]);

      // P -> sP (own wave's rows only; swizzled, conflict-free per round-2/3 PMC)
#pragma unroll
      for (int nj = 0; nj < 4; ++nj) {
        int chunk = nj * 2 + (lr >> 3);
#pragma unroll
        for (int r = 0; r < 4; ++r) {
          int row = w * 32 + mi * 16 + lq * 4 + r;
          sP[row * 64 + ((chunk ^ (row & 7)) << 3) + (lr & 7)] = f2bf_fast(s[mi][nj][r]);
        }
      }
    }
    asm volatile("s_waitcnt lgkmcnt(0)" ::: "memory");

    // O += P V
#pragma unroll
    for (int kk = 0; kk < 64; kk += 32) {
      const int c8 = (kk >> 3) + lq;
      bf16x8 pa[2], vf[4];
#pragma unroll
      for (int mi = 0; mi < 2; ++mi) pa[mi] = ldsfrag(sP, w * 32 + mi * 16 + lr, c8);
#pragma unroll
      for (int nj = 0; nj < 4; ++nj) vf[nj] = ldsfrag(cV, nj * 16 + lr, c8);
#pragma unroll
      for (int mi = 0; mi < 2; ++mi)
#pragma unroll
        for (int nj = 0; nj < 4; ++nj)
          o[mi][nj] = __builtin_amdgcn_mfma_f32_16x16x32_bf16(pa[mi], vf[nj], o[mi][nj], 0, 0, 0);
    }
  }

  // y[b][t][h*64+hd] bf16
  const int b = bh >> 4, h = bh & 15;
#pragma unroll
  for (int mi = 0; mi < 2; ++mi)
#pragma unroll
    for (int r = 0; r < 4; ++r) {
      float inv = 1.0f / lrow[mi][r];
      int row = q0 + w * 32 + mi * 16 + lq * 4 + r;
      size_t base = ((size_t)(b * 2048 + row)) * 1024 + h * 64;
#pragma unroll
      for (int nj = 0; nj < 4; ++nj) yb[base + nj * 16 + lr] = f2bf(o[mi][nj][r] * inv);
    }
}

// ---------------- GEMM2: out = y @ W_proj + b (fp32 out) ----------------
__global__ __launch_bounds__(256) void k_gemm_proj(const u16* __restrict__ ybuf,
                                                   const u16* __restrict__ Wt,
                                                   const float* __restrict__ bias,
                                                   float* __restrict__ out) {
  __shared__ u16 sA[128 * 64], sB[128 * 64];
  f32x4 acc[4][4];
#pragma unroll
  for (int mi = 0; mi < 4; ++mi)
#pragma unroll
    for (int ni = 0; ni < 4; ++ni) acc[mi][ni] = (f32x4){0.f, 0.f, 0.f, 0.f};
  const int m0 = blockIdx.y * 128, n0 = blockIdx.x * 128;
  gemm_core(ybuf, Wt, 1024, m0, n0, sA, sB, acc);

  const int lane = threadIdx.x & 63, w = threadIdx.x >> 6;
  const int wm = (w >> 1) << 6, wn = (w & 1) << 6, lr = lane & 15, lq = lane >> 4;
#pragma unroll
  for (int mi = 0; mi < 4; ++mi) {
    int gm = m0 + wm + mi * 16 + lq * 4;
#pragma unroll
    for (int ni = 0; ni < 4; ++ni) {
      int gn = n0 + wn + ni * 16 + lr;
      float bv = bias[gn];
#pragma unroll
      for (int r = 0; r < 4; ++r) out[(size_t)(gm + r) * 1024 + gn] = acc[mi][ni][r] + bv;
    }
  }
}

extern "C" void kernel_launch(void* const* d_in, const int* in_sizes, int n_in,
                              void* d_out, int out_size, void* d_ws, size_t ws_size,
                              hipStream_t stream) {
  const float* x = (const float*)d_in[0];       // [2,2048,1024]
  const float* W_attn = (const float*)d_in[1];  // [1024,3072]
  const float* b_attn = (const float*)d_in[2];  // [3072]
  const float* W_proj = (const float*)d_in[3];  // [1024,1024]
  const float* b_proj = (const float*)d_in[4];  // [1024]
  float* out = (float*)d_out;                   // [2,2048,1024] fp32

  u16* ws = (u16*)d_ws;
  u16* xb = ws;                   // 4096x1024 bf16
  u16* WaT = ws + 4194304;        // 3072x1024 (W_attn^T)
  u16* WpT = ws + 7340032;        // 1024x1024 (W_proj^T)
  u16* qbuf = ws + 8388608;       // [32][2048][64]
  u16* kbuf = ws + 12582912;      // [32][2048][64]
  u16* vtb = ws + 16777216;       // [32][64][2048]
  u16* ybuf = ws + 20971520;      // [4096][1024]

  k_cvt<<<dim3(2048), dim3(256), 0, stream>>>(x, xb);
  k_tr<<<dim3(48, 16), dim3(256), 0, stream>>>(W_attn, WaT, 1024, 3072);
  k_tr<<<dim3(16, 16), dim3(256), 0, stream>>>(W_proj, WpT, 1024, 1024);
  k_gemm_qkv<<<dim3(24, 32), dim3(256), 0, stream>>>(xb, WaT, b_attn, qbuf, kbuf, vtb);
  k_attn<<<dim3(512), dim3(256), 0, stream>>>(qbuf, kbuf, vtb, ybuf);
  k_gemm_proj<<<dim3(8, 32), dim3(256), 0, stream>>>(ybuf, WpT, b_proj, out);
}

// Round 5
// 198.503 us; speedup vs baseline: 1.3812x; 1.1453x over previous
//
#include <hip/hip_runtime.h>

typedef unsigned short u16;
typedef unsigned int u32;
typedef short bf16x8 __attribute__((ext_vector_type(8)));
typedef float f32x4 __attribute__((ext_vector_type(4)));

__device__ __forceinline__ u16 f2bf(float f) {
  union { float f; u32 u; } v; v.f = f;
  u32 r = v.u + 0x7fffu + ((v.u >> 16) & 1u);
  return (u16)(r >> 16);
}
// cheap round-half-up (P matrix only; values in [0,1])
__device__ __forceinline__ u16 f2bf_fast(float f) {
  union { float f; u32 u; } v; v.f = f;
  return (u16)((v.u + 0x8000u) >> 16);
}
__device__ __forceinline__ float fexp2(float x) {
#if __has_builtin(__builtin_amdgcn_exp2f)
  return __builtin_amdgcn_exp2f(x);
#else
  return exp2f(x);
#endif
}

__device__ __forceinline__ void gld_lds16(const u16* g, u16* l) {
  __builtin_amdgcn_global_load_lds(
      (__attribute__((address_space(1))) u32*)(g),
      (__attribute__((address_space(3))) u32*)(l),
      16, 0, 0);
}

// LDS fragment read with XOR-16B swizzle (rows of 64 bf16 = 8 chunks of 16B).
__device__ __forceinline__ bf16x8 ldsfrag(const u16* base, int row, int c8) {
  return *(const bf16x8*)(base + row * 64 + ((c8 ^ (row & 7)) << 3));
}

// DPP cross-lane (within 16-lane rows): VALU-pipe reduction.
template <int CTRL>
__device__ __forceinline__ float dppf(float x) {
  return __int_as_float(__builtin_amdgcn_update_dpp(0, __float_as_int(x), CTRL, 0xf, 0xf, true));
}
__device__ __forceinline__ float red16_max(float x) {
  x = fmaxf(x, dppf<0xB1>(x));
  x = fmaxf(x, dppf<0x4E>(x));
  x = fmaxf(x, dppf<0x141>(x));
  x = fmaxf(x, dppf<0x140>(x));
  return x;
}
__device__ __forceinline__ float red16_sum(float x) {
  x += dppf<0xB1>(x);
  x += dppf<0x4E>(x);
  x += dppf<0x141>(x);
  x += dppf<0x140>(x);
  return x;
}

// ---------------- fp32 -> bf16 convert (x) ----------------
__global__ __launch_bounds__(256) void k_cvt(const float* __restrict__ s, u16* __restrict__ d) {
  int i = (blockIdx.x * 256 + threadIdx.x) * 8;
  const float4* p = (const float4*)(s + i);
  float4 a = p[0], b = p[1];
  uint4 o;
  o.x = (u32)f2bf(a.x) | ((u32)f2bf(a.y) << 16);
  o.y = (u32)f2bf(a.z) | ((u32)f2bf(a.w) << 16);
  o.z = (u32)f2bf(b.x) | ((u32)f2bf(b.y) << 16);
  o.w = (u32)f2bf(b.z) | ((u32)f2bf(b.w) << 16);
  *(uint4*)(d + i) = o;
}

// ---------------- fp32 [rows][cols] -> bf16 transposed [cols][rows] ----------------
__global__ __launch_bounds__(256) void k_tr(const float* __restrict__ s, u16* __restrict__ d,
                                            int rows, int cols) {
  __shared__ float t[64][65];
  int c0 = blockIdx.x * 64, r0 = blockIdx.y * 64;
  int tx = threadIdx.x & 63, ty = threadIdx.x >> 6;
#pragma unroll
  for (int i = ty; i < 64; i += 4)
    t[i][tx] = s[(size_t)(r0 + i) * cols + c0 + tx];
  __syncthreads();
#pragma unroll
  for (int i = ty; i < 64; i += 4)
    d[(size_t)(c0 + i) * rows + r0 + tx] = f2bf(t[tx][i]);
}

// ---------------- shared 128x128x(K) bf16 MFMA GEMM core ----------------
__device__ __forceinline__ void gemm_core(const u16* __restrict__ A, const u16* __restrict__ Bt,
                                          const int K, const int m0, const int n0,
                                          u16* sA, u16* sB, f32x4 acc[4][4]) {
  const int tid = threadIdx.x;
  const int lane = tid & 63, w = tid >> 6;
  const int wm = (w >> 1) << 6, wn = (w & 1) << 6;
  const int lr = lane & 15, lq = lane >> 4;
  const int srow = tid >> 3;
  const int gcol = ((tid & 7) ^ (srow & 7)) << 3;
  const u16* ag = A + (size_t)(m0 + srow) * K + gcol;
  const u16* bg = Bt + (size_t)(n0 + srow) * K + gcol;
  u16* la = sA + w * 512;
  u16* lb = sB + w * 512;

  for (int k0 = 0; k0 < K; k0 += 64) {
    __syncthreads();
#pragma unroll
    for (int r = 0; r < 4; ++r) {
      gld_lds16(ag + (size_t)r * 32 * K + k0, la + r * 2048);
      gld_lds16(bg + (size_t)r * 32 * K + k0, lb + r * 2048);
    }
    __syncthreads();
#pragma unroll
    for (int kk = 0; kk < 64; kk += 32) {
      const int c8 = (kk >> 3) + lq;
      bf16x8 af[4], bfr[4];
#pragma unroll
      for (int i = 0; i < 4; ++i) {
        af[i] = ldsfrag(sA, wm + i * 16 + lr, c8);
        bfr[i] = ldsfrag(sB, wn + i * 16 + lr, c8);
      }
#pragma unroll
      for (int mi = 0; mi < 4; ++mi)
#pragma unroll
        for (int ni = 0; ni < 4; ++ni)
          acc[mi][ni] = __builtin_amdgcn_mfma_f32_16x16x32_bf16(af[mi], bfr[ni], acc[mi][ni], 0, 0, 0);
    }
  }
}

// ---------------- GEMM1a: q,k = x @ W_attn[:, :2048] + b, scattered to head layouts ----------------
__global__ __launch_bounds__(256) void k_gemm_qk(const u16* __restrict__ xb,
                                                 const u16* __restrict__ Wt,
                                                 const float* __restrict__ bias,
                                                 u16* __restrict__ qb, u16* __restrict__ kb) {
  __shared__ u16 sA[128 * 64], sB[128 * 64];
  f32x4 acc[4][4];
#pragma unroll
  for (int mi = 0; mi < 4; ++mi)
#pragma unroll
    for (int ni = 0; ni < 4; ++ni) acc[mi][ni] = (f32x4){0.f, 0.f, 0.f, 0.f};
  const int m0 = blockIdx.y * 128, n0 = blockIdx.x * 128;
  gemm_core(xb, Wt, 1024, m0, n0, sA, sB, acc);

  const int lane = threadIdx.x & 63, w = threadIdx.x >> 6;
  const int wm = (w >> 1) << 6, wn = (w & 1) << 6, lr = lane & 15, lq = lane >> 4;
#pragma unroll
  for (int mi = 0; mi < 4; ++mi) {
    int gm = m0 + wm + mi * 16 + lq * 4;
#pragma unroll
    for (int ni = 0; ni < 4; ++ni) {
      int gn = n0 + wn + ni * 16 + lr;
      float bv = bias[gn];
      int which = gn >> 10, head = (gn >> 6) & 15, hd = gn & 63;
#pragma unroll
      for (int r = 0; r < 4; ++r) {
        int row = gm + r;
        int b = row >> 11, t = row & 2047;
        float v = acc[mi][ni][r] + bv;
        size_t bh = (size_t)(b * 16 + head);
        if (which == 0)
          qb[(bh * 2048 + t) * 64 + hd] = f2bf(v * 0.125f);  // fold 1/sqrt(64)
        else
          kb[(bh * 2048 + t) * 64 + hd] = f2bf(v);
      }
    }
  }
}

// ---------------- GEMM1b: vt[dv][t] = W_v^T x^T  (coalesced vtb stores) ----------------
// A = WaT rows 2048..3071 (M=1024=dv, K=1024), Bt = xb (N=4096=t, K=1024).
// C[dv][t] = (x @ W_attn)[t][2048+dv] = v[t][dv] -> exactly vtb's [head-hd][t] layout.
__global__ __launch_bounds__(256) void k_gemm_v(const u16* __restrict__ xb,
                                                const u16* __restrict__ Wt,
                                                const float* __restrict__ bias,
                                                u16* __restrict__ vtb) {
  __shared__ u16 sA[128 * 64], sB[128 * 64];
  f32x4 acc[4][4];
#pragma unroll
  for (int mi = 0; mi < 4; ++mi)
#pragma unroll
    for (int ni = 0; ni < 4; ++ni) acc[mi][ni] = (f32x4){0.f, 0.f, 0.f, 0.f};
  const int m0 = blockIdx.y * 128, n0 = blockIdx.x * 128;
  gemm_core(Wt + 2048 * 1024, xb, 1024, m0, n0, sA, sB, acc);

  const int lane = threadIdx.x & 63, w = threadIdx.x >> 6;
  const int wm = (w >> 1) << 6, wn = (w & 1) << 6, lr = lane & 15, lq = lane >> 4;
#pragma unroll
  for (int mi = 0; mi < 4; ++mi) {
    int gm = m0 + wm + mi * 16 + lq * 4;  // dv base (multiple of 4)
    float4 bv = *(const float4*)(bias + 2048 + gm);
#pragma unroll
    for (int ni = 0; ni < 4; ++ni) {
      int gn = n0 + wn + ni * 16 + lr;  // t global (lanes contiguous -> coalesced)
      int b = gn >> 11, tt = gn & 2047;
#pragma unroll
      for (int r = 0; r < 4; ++r) {
        int dv = gm + r;
        float v = acc[mi][ni][r] + ((const float*)&bv)[r];
        vtb[((size_t)(b * 1024 + dv)) * 2048 + tt] = f2bf(v);
      }
    }
  }
}

// ---------------- flash attention v5: BQ=64, Q in regs, 4 blocks/CU ----------------
// 1024 blocks (one per (bh,qt)); LDS=40KB -> 4 blocks/CU = 16 waves/CU = 4/SIMD.
// qt mapping makes the 4 blocks landing on one CU (l, l+256, l+512, l+768 under
// mod-256 round-robin, round-2 evidence) sum to exactly 62 -> 66 kv-rounds per CU,
// all resident from t=0 (fixes round-4's makespan imbalance). Q A-fragments live
// in 8 VGPRs (loaded once): no sQ, no per-iter Q ds_reads.
__global__ __launch_bounds__(256, 4) void k_attn(const u16* __restrict__ qb,
                                                 const u16* __restrict__ kb,
                                                 const u16* __restrict__ vtb,
                                                 u16* __restrict__ yb) {
  __shared__ u16 sK[2][64 * 64];  // 16KB dbuf
  __shared__ u16 sV[2][64 * 64];  // 16KB dbuf, [hd][kv]
  __shared__ u16 sP[64 * 64];     // 8KB, XOR-swizzled  -> 40KB total

  const int tid = threadIdx.x;
  const int lane = tid & 63, w = tid >> 6;  // w in 0..3, wave owns 16 q-rows
  const int lr = lane & 15, lq = lane >> 4;
  const int l = blockIdx.x;
  const int bh = l & 31;
  const int i = l >> 5;
  int qt;
  if (i < 8) qt = 31 - i;        // heavy first
  else if (i < 16) qt = i - 8;   // light
  else if (i < 24) qt = 39 - i;  // medium-heavy
  else qt = i - 16;              // medium-light   (per-CU qt sum = 62)
  const int q0 = qt << 6;

  const u16* qh = qb + (size_t)bh * (2048 * 64);
  const u16* kh = kb + (size_t)bh * (2048 * 64);
  const u16* vh = vtb + (size_t)bh * (64 * 2048);

  // Q A-fragments to registers: A[m=lr][k=lq*8+j], rows q0+w*16+lr
  bf16x8 qreg[2];
  {
    const u16* qp = qh + (size_t)(q0 + w * 16 + lr) * 64 + lq * 8;
    qreg[0] = *(const bf16x8*)(qp);
    qreg[1] = *(const bf16x8*)(qp + 32);
  }

  const int srow = tid >> 3;                       // 0..31
  const int gcol = ((tid & 7) ^ (srow & 7)) << 3;  // swizzled 16B chunk

  {  // KV tile 0 -> buf 0
    u16* lk = sK[0] + w * 512;
    u16* lv = sV[0] + w * 512;
#pragma unroll
    for (int r = 0; r < 2; ++r) {
      gld_lds16(kh + (size_t)(r * 32 + srow) * 64 + gcol, lk + r * 2048);
      gld_lds16(vh + (size_t)(r * 32 + srow) * 2048 + gcol, lv + r * 2048);
    }
  }

  const float L2E = 1.44269504f;
  f32x4 o[4];
  float mL2[4], lrow[4];
#pragma unroll
  for (int j = 0; j < 4; ++j) {
    o[j] = (f32x4){0.f, 0.f, 0.f, 0.f};
    mL2[j] = -1e30f;
    lrow[j] = 0.f;
  }

  const int ntiles = qt + 1;
  for (int it = 0; it < ntiles; ++it) {
    __syncthreads();        // publishes buf[it&1]
    if (it + 1 < ntiles) {  // prefetch next tile into the other buffer
      const int nkv = (it + 1) << 6;
      const int nb = (it + 1) & 1;
      u16* lk = sK[nb] + w * 512;
      u16* lv = sV[nb] + w * 512;
#pragma unroll
      for (int r = 0; r < 2; ++r) {
        gld_lds16(kh + (size_t)(nkv + r * 32 + srow) * 64 + gcol, lk + r * 2048);
        gld_lds16(vh + (size_t)(r * 32 + srow) * 2048 + nkv + gcol, lv + r * 2048);
      }
    }
    const u16* cK = sK[it & 1];
    const u16* cV = sV[it & 1];

    // S = Q K^T : wave owns 16 q rows x 64 kv cols; Q from registers
    f32x4 s[4];
#pragma unroll
    for (int nj = 0; nj < 4; ++nj) s[nj] = (f32x4){0.f, 0.f, 0.f, 0.f};
#pragma unroll
    for (int kk = 0; kk < 64; kk += 32) {
      const int c8 = (kk >> 3) + lq;
      bf16x8 kf[4];
#pragma unroll
      for (int nj = 0; nj < 4; ++nj) kf[nj] = ldsfrag(cK, nj * 16 + lr, c8);
#pragma unroll
      for (int nj = 0; nj < 4; ++nj)
        s[nj] = __builtin_amdgcn_mfma_f32_16x16x32_bf16(qreg[kk >> 5], kf[nj], s[nj], 0, 0, 0);
    }

    if (it == qt) {  // diagonal tile: mask col > row (block-local)
      int rloc = w * 16 + lq * 4;
#pragma unroll
      for (int nj = 0; nj < 4; ++nj) {
        int cloc = nj * 16 + lr;
#pragma unroll
        for (int r = 0; r < 4; ++r)
          if (cloc > rloc + r) s[nj][r] = -1e30f;
      }
    }

    // online softmax in exp2 domain (rows = lq*4+r across 16 lanes lr)
    float al[4];
#pragma unroll
    for (int r = 0; r < 4; ++r) {
      float mx = fmaxf(fmaxf(s[0][r], s[1][r]), fmaxf(s[2][r], s[3][r]));
      mx = red16_max(mx) * L2E;
      float mn = fmaxf(mL2[r], mx);
      al[r] = fexp2(mL2[r] - mn);
      mL2[r] = mn;
    }
#pragma unroll
    for (int nj = 0; nj < 4; ++nj)
#pragma unroll
      for (int r = 0; r < 4; ++r) o[nj][r] *= al[r];
    float rs[4];
#pragma unroll
    for (int r = 0; r < 4; ++r) rs[r] = 0.f;
#pragma unroll
    for (int nj = 0; nj < 4; ++nj)
#pragma unroll
      for (int r = 0; r < 4; ++r) {
        float p = fexp2(fmaf(s[nj][r], L2E, -mL2[r]));
        s[nj][r] = p;
        rs[r] += p;
      }
#pragma unroll
    for (int r = 0; r < 4; ++r) lrow[r] = lrow[r] * al[r] + red16_sum(rs[r]);

    // P -> sP (own wave's 16 rows only; swizzled, conflict-free)
#pragma unroll
    for (int nj = 0; nj < 4; ++nj) {
      int chunk = nj * 2 + (lr >> 3);
#pragma unroll
      for (int r = 0; r < 4; ++r) {
        int row = w * 16 + lq * 4 + r;
        sP[row * 64 + ((chunk ^ (row & 7)) << 3) + (lr & 7)] = f2bf_fast(s[nj][r]);
      }
    }
    asm volatile("s_waitcnt lgkmcnt(0)" ::: "memory");

    // O += P V
#pragma unroll
    for (int kk = 0; kk < 64; kk += 32) {
      const int c8 = (kk >> 3) + lq;
      bf16x8 pa = ldsfrag(sP, w * 16 + lr, c8);
      bf16x8 vf[4];
#pragma unroll
      for (int nj = 0; nj < 4; ++nj) vf[nj] = ldsfrag(cV, nj * 16 + lr, c8);
#pragma unroll
      for (int nj = 0; nj < 4; ++nj)
        o[nj] = __builtin_amdgcn_mfma_f32_16x16x32_bf16(pa, vf[nj], o[nj], 0, 0, 0);
    }
  }

  // y[b][t][h*64+hd] bf16
  const int b = bh >> 4, h = bh & 15;
#pragma unroll
  for (int r = 0; r < 4; ++r) {
    float inv = 1.0f / lrow[r];
    int row = q0 + w * 16 + lq * 4 + r;
    size_t base = ((size_t)(b * 2048 + row)) * 1024 + h * 64;
#pragma unroll
    for (int nj = 0; nj < 4; ++nj) yb[base + nj * 16 + lr] = f2bf(o[nj][r] * inv);
  }
}

// ---------------- GEMM2: out = y @ W_proj + b (fp32 out) ----------------
__global__ __launch_bounds__(256) void k_gemm_proj(const u16* __restrict__ ybuf,
                                                   const u16* __restrict__ Wt,
                                                   const float* __restrict__ bias,
                                                   float* __restrict__ out) {
  __shared__ u16 sA[128 * 64], sB[128 * 64];
  f32x4 acc[4][4];
#pragma unroll
  for (int mi = 0; mi < 4; ++mi)
#pragma unroll
    for (int ni = 0; ni < 4; ++ni) acc[mi][ni] = (f32x4){0.f, 0.f, 0.f, 0.f};
  const int m0 = blockIdx.y * 128, n0 = blockIdx.x * 128;
  gemm_core(ybuf, Wt, 1024, m0, n0, sA, sB, acc);

  const int lane = threadIdx.x & 63, w = threadIdx.x >> 6;
  const int wm = (w >> 1) << 6, wn = (w & 1) << 6, lr = lane & 15, lq = lane >> 4;
#pragma unroll
  for (int mi = 0; mi < 4; ++mi) {
    int gm = m0 + wm + mi * 16 + lq * 4;
#pragma unroll
    for (int ni = 0; ni < 4; ++ni) {
      int gn = n0 + wn + ni * 16 + lr;
      float bv = bias[gn];
#pragma unroll
      for (int r = 0; r < 4; ++r) out[(size_t)(gm + r) * 1024 + gn] = acc[mi][ni][r] + bv;
    }
  }
}

extern "C" void kernel_launch(void* const* d_in, const int* in_sizes, int n_in,
                              void* d_out, int out_size, void* d_ws, size_t ws_size,
                              hipStream_t stream) {
  const float* x = (const float*)d_in[0];       // [2,2048,1024]
  const float* W_attn = (const float*)d_in[1];  // [1024,3072]
  const float* b_attn = (const float*)d_in[2];  // [3072]
  const float* W_proj = (const float*)d_in[3];  // [1024,1024]
  const float* b_proj = (const float*)d_in[4];  // [1024]
  float* out = (float*)d_out;                   // [2,2048,1024] fp32

  u16* ws = (u16*)d_ws;
  u16* xb = ws;                   // 4096x1024 bf16
  u16* WaT = ws + 4194304;        // 3072x1024 (W_attn^T)
  u16* WpT = ws + 7340032;        // 1024x1024 (W_proj^T)
  u16* qbuf = ws + 8388608;       // [32][2048][64]
  u16* kbuf = ws + 12582912;      // [32][2048][64]
  u16* vtb = ws + 16777216;       // [32][64][2048]
  u16* ybuf = ws + 20971520;      // [4096][1024]

  k_cvt<<<dim3(2048), dim3(256), 0, stream>>>(x, xb);
  k_tr<<<dim3(48, 16), dim3(256), 0, stream>>>(W_attn, WaT, 1024, 3072);
  k_tr<<<dim3(16, 16), dim3(256), 0, stream>>>(W_proj, WpT, 1024, 1024);
  k_gemm_qk<<<dim3(16, 32), dim3(256), 0, stream>>>(xb, WaT, b_attn, qbuf, kbuf);
  k_gemm_v<<<dim3(32, 8), dim3(256), 0, stream>>>(xb, WaT, b_attn, vtb);
  k_attn<<<dim3(1024), dim3(256), 0, stream>>>(qbuf, kbuf, vtb, ybuf);
  k_gemm_proj<<<dim3(8, 32), dim3(256), 0, stream>>>(ybuf, WpT, b_proj, out);
}

// Round 6
// 187.211 us; speedup vs baseline: 1.4645x; 1.0603x over previous
//
#include <hip/hip_runtime.h>

typedef unsigned short u16;
typedef unsigned int u32;
typedef short bf16x8 __attribute__((ext_vector_type(8)));
typedef float f32x4 __attribute__((ext_vector_type(4)));

__device__ __forceinline__ u16 f2bf(float f) {
  union { float f; u32 u; } v; v.f = f;
  u32 r = v.u + 0x7fffu + ((v.u >> 16) & 1u);
  return (u16)(r >> 16);
}
// cheap round-half-up (P matrix only; values in [0,1])
__device__ __forceinline__ u16 f2bf_fast(float f) {
  union { float f; u32 u; } v; v.f = f;
  return (u16)((v.u + 0x8000u) >> 16);
}
__device__ __forceinline__ float fexp2(float x) {
#if __has_builtin(__builtin_amdgcn_exp2f)
  return __builtin_amdgcn_exp2f(x);
#else
  return exp2f(x);
#endif
}

__device__ __forceinline__ void gld_lds16(const u16* g, u16* l) {
  __builtin_amdgcn_global_load_lds(
      (__attribute__((address_space(1))) u32*)(g),
      (__attribute__((address_space(3))) u32*)(l),
      16, 0, 0);
}

// LDS fragment read with XOR-16B swizzle (rows of 64 bf16 = 8 chunks of 16B).
__device__ __forceinline__ bf16x8 ldsfrag(const u16* base, int row, int c8) {
  return *(const bf16x8*)(base + row * 64 + ((c8 ^ (row & 7)) << 3));
}

// DPP cross-lane (within 16-lane rows): VALU-pipe reduction.
template <int CTRL>
__device__ __forceinline__ float dppf(float x) {
  return __int_as_float(__builtin_amdgcn_update_dpp(0, __float_as_int(x), CTRL, 0xf, 0xf, true));
}
__device__ __forceinline__ float red16_max(float x) {
  x = fmaxf(x, dppf<0xB1>(x));
  x = fmaxf(x, dppf<0x4E>(x));
  x = fmaxf(x, dppf<0x141>(x));
  x = fmaxf(x, dppf<0x140>(x));
  return x;
}
__device__ __forceinline__ float red16_sum(float x) {
  x += dppf<0xB1>(x);
  x += dppf<0x4E>(x);
  x += dppf<0x141>(x);
  x += dppf<0x140>(x);
  return x;
}

// ---------------- prep (fused): x fp32->bf16, W_attn^T, W_proj^T ----------------
__device__ __forceinline__ void tr_body(const float* __restrict__ s, u16* __restrict__ d,
                                        int rows, int cols, int bx, int by,
                                        float (*t)[65]) {
  int c0 = bx * 64, r0 = by * 64;
  int tx = threadIdx.x & 63, ty = threadIdx.x >> 6;
#pragma unroll
  for (int i = ty; i < 64; i += 4)
    t[i][tx] = s[(size_t)(r0 + i) * cols + c0 + tx];
  __syncthreads();
#pragma unroll
  for (int i = ty; i < 64; i += 4)
    d[(size_t)(c0 + i) * rows + r0 + tx] = f2bf(t[tx][i]);
}

__global__ __launch_bounds__(256) void k_prep(const float* __restrict__ x, u16* __restrict__ xb,
                                              const float* __restrict__ Wa, u16* __restrict__ WaT,
                                              const float* __restrict__ Wp, u16* __restrict__ WpT) {
  __shared__ float t[64][65];
  const int id = blockIdx.x;
  if (id < 2048) {  // cvt: 2048 blocks x 256 thr x 8 elems = 4096*1024
    int i = (id * 256 + threadIdx.x) * 8;
    const float4* p = (const float4*)(x + i);
    float4 a = p[0], b = p[1];
    uint4 o;
    o.x = (u32)f2bf(a.x) | ((u32)f2bf(a.y) << 16);
    o.y = (u32)f2bf(a.z) | ((u32)f2bf(a.w) << 16);
    o.z = (u32)f2bf(b.x) | ((u32)f2bf(b.y) << 16);
    o.w = (u32)f2bf(b.z) | ((u32)f2bf(b.w) << 16);
    *(uint4*)(xb + i) = o;
  } else if (id < 2816) {  // W_attn [1024][3072] -> [3072][1024]
    int q = id - 2048;
    tr_body(Wa, WaT, 1024, 3072, q % 48, q / 48, t);
  } else {  // W_proj [1024][1024] -> [1024][1024]^T
    int q = id - 2816;
    tr_body(Wp, WpT, 1024, 1024, q & 15, q >> 4, t);
  }
}

// ---------------- shared 128x128x(K) bf16 MFMA GEMM core ----------------
__device__ __forceinline__ void gemm_core(const u16* __restrict__ A, const u16* __restrict__ Bt,
                                          const int K, const int m0, const int n0,
                                          u16* sA, u16* sB, f32x4 acc[4][4]) {
  const int tid = threadIdx.x;
  const int lane = tid & 63, w = tid >> 6;
  const int wm = (w >> 1) << 6, wn = (w & 1) << 6;
  const int lr = lane & 15, lq = lane >> 4;
  const int srow = tid >> 3;
  const int gcol = ((tid & 7) ^ (srow & 7)) << 3;
  const u16* ag = A + (size_t)(m0 + srow) * K + gcol;
  const u16* bg = Bt + (size_t)(n0 + srow) * K + gcol;
  u16* la = sA + w * 512;
  u16* lb = sB + w * 512;

  for (int k0 = 0; k0 < K; k0 += 64) {
    __syncthreads();
#pragma unroll
    for (int r = 0; r < 4; ++r) {
      gld_lds16(ag + (size_t)r * 32 * K + k0, la + r * 2048);
      gld_lds16(bg + (size_t)r * 32 * K + k0, lb + r * 2048);
    }
    __syncthreads();
#pragma unroll
    for (int kk = 0; kk < 64; kk += 32) {
      const int c8 = (kk >> 3) + lq;
      bf16x8 af[4], bfr[4];
#pragma unroll
      for (int i = 0; i < 4; ++i) {
        af[i] = ldsfrag(sA, wm + i * 16 + lr, c8);
        bfr[i] = ldsfrag(sB, wn + i * 16 + lr, c8);
      }
#pragma unroll
      for (int mi = 0; mi < 4; ++mi)
#pragma unroll
        for (int ni = 0; ni < 4; ++ni)
          acc[mi][ni] = __builtin_amdgcn_mfma_f32_16x16x32_bf16(af[mi], bfr[ni], acc[mi][ni], 0, 0, 0);
    }
  }
}

// ---------------- GEMM1 (fused): qk (512 blocks) + v (256 blocks) ----------------
// All 768 blocks do identical work (16 K-iters) -> balanced 3 blocks/CU.
__global__ __launch_bounds__(256) void k_gemm_qkv(const u16* __restrict__ xb,
                                                  const u16* __restrict__ Wt,
                                                  const float* __restrict__ bias,
                                                  u16* __restrict__ qb, u16* __restrict__ kb,
                                                  u16* __restrict__ vtb) {
  __shared__ u16 sA[128 * 64], sB[128 * 64];
  f32x4 acc[4][4];
#pragma unroll
  for (int mi = 0; mi < 4; ++mi)
#pragma unroll
    for (int ni = 0; ni < 4; ++ni) acc[mi][ni] = (f32x4){0.f, 0.f, 0.f, 0.f};

  const int id = blockIdx.x;
  const int lane = threadIdx.x & 63, w = threadIdx.x >> 6;
  const int wm = (w >> 1) << 6, wn = (w & 1) << 6, lr = lane & 15, lq = lane >> 4;

  if (id < 512) {
    // qk: C[t][gn], gn in [0,2048): q then k
    const int m0 = (id >> 4) * 128, n0 = (id & 15) * 128;
    gemm_core(xb, Wt, 1024, m0, n0, sA, sB, acc);
#pragma unroll
    for (int mi = 0; mi < 4; ++mi) {
      int gm = m0 + wm + mi * 16 + lq * 4;
#pragma unroll
      for (int ni = 0; ni < 4; ++ni) {
        int gn = n0 + wn + ni * 16 + lr;
        float bv = bias[gn];
        int which = gn >> 10, head = (gn >> 6) & 15, hd = gn & 63;
#pragma unroll
        for (int r = 0; r < 4; ++r) {
          int row = gm + r;
          int b = row >> 11, tt = row & 2047;
          float v = acc[mi][ni][r] + bv;
          size_t bh = (size_t)(b * 16 + head);
          if (which == 0)
            qb[(bh * 2048 + tt) * 64 + hd] = f2bf(v * 0.125f);  // fold 1/sqrt(64)
          else
            kb[(bh * 2048 + tt) * 64 + hd] = f2bf(v);
        }
      }
    }
  } else {
    // v^T: A = WaT rows 2048..3071 (M=1024=dv), Bt = xb (N=4096=t)
    const int t2 = id - 512;
    const int m0 = (t2 >> 5) * 128, n0 = (t2 & 31) * 128;
    gemm_core(Wt + 2048 * 1024, xb, 1024, m0, n0, sA, sB, acc);
#pragma unroll
    for (int mi = 0; mi < 4; ++mi) {
      int gm = m0 + wm + mi * 16 + lq * 4;  // dv base (multiple of 4)
      float4 bv = *(const float4*)(bias + 2048 + gm);
#pragma unroll
      for (int ni = 0; ni < 4; ++ni) {
        int gn = n0 + wn + ni * 16 + lr;  // t global (coalesced)
        int b = gn >> 11, tt = gn & 2047;
#pragma unroll
        for (int r = 0; r < 4; ++r) {
          int dv = gm + r;
          float v = acc[mi][ni][r] + ((const float*)&bv)[r];
          vtb[((size_t)(b * 1024 + dv)) * 2048 + tt] = f2bf(v);
        }
      }
    }
  }
}

// ---------------- flash attention v5: BQ=64, Q in regs, 4 blocks/CU ----------------
__global__ __launch_bounds__(256, 4) void k_attn(const u16* __restrict__ qb,
                                                 const u16* __restrict__ kb,
                                                 const u16* __restrict__ vtb,
                                                 u16* __restrict__ yb) {
  __shared__ u16 sK[2][64 * 64];  // 16KB dbuf
  __shared__ u16 sV[2][64 * 64];  // 16KB dbuf, [hd][kv]
  __shared__ u16 sP[64 * 64];     // 8KB, XOR-swizzled  -> 40KB total

  const int tid = threadIdx.x;
  const int lane = tid & 63, w = tid >> 6;  // wave owns 16 q-rows
  const int lr = lane & 15, lq = lane >> 4;
  const int l = blockIdx.x;
  const int bh = l & 31;
  const int i = l >> 5;
  int qt;
  if (i < 8) qt = 31 - i;
  else if (i < 16) qt = i - 8;
  else if (i < 24) qt = 39 - i;
  else qt = i - 16;  // per-CU qt sum = 62 under mod-256 placement
  const int q0 = qt << 6;

  const u16* qh = qb + (size_t)bh * (2048 * 64);
  const u16* kh = kb + (size_t)bh * (2048 * 64);
  const u16* vh = vtb + (size_t)bh * (64 * 2048);

  // Q A-fragments in registers: A[m=lr][k=lq*8+j]
  bf16x8 qreg[2];
  {
    const u16* qp = qh + (size_t)(q0 + w * 16 + lr) * 64 + lq * 8;
    qreg[0] = *(const bf16x8*)(qp);
    qreg[1] = *(const bf16x8*)(qp + 32);
  }

  const int srow = tid >> 3;                       // 0..31
  const int gcol = ((tid & 7) ^ (srow & 7)) << 3;  // swizzled 16B chunk

  {  // KV tile 0 -> buf 0
    u16* lk = sK[0] + w * 512;
    u16* lv = sV[0] + w * 512;
#pragma unroll
    for (int r = 0; r < 2; ++r) {
      gld_lds16(kh + (size_t)(r * 32 + srow) * 64 + gcol, lk + r * 2048);
      gld_lds16(vh + (size_t)(r * 32 + srow) * 2048 + gcol, lv + r * 2048);
    }
  }

  const float L2E = 1.44269504f;
  f32x4 o[4];
  float mL2[4], lrow[4];
#pragma unroll
  for (int j = 0; j < 4; ++j) {
    o[j] = (f32x4){0.f, 0.f, 0.f, 0.f};
    mL2[j] = -1e30f;
    lrow[j] = 0.f;
  }

  const int ntiles = qt + 1;
  for (int it = 0; it < ntiles; ++it) {
    __syncthreads();
    if (it + 1 < ntiles) {
      const int nkv = (it + 1) << 6;
      const int nb = (it + 1) & 1;
      u16* lk = sK[nb] + w * 512;
      u16* lv = sV[nb] + w * 512;
#pragma unroll
      for (int r = 0; r < 2; ++r) {
        gld_lds16(kh + (size_t)(nkv + r * 32 + srow) * 64 + gcol, lk + r * 2048);
        gld_lds16(vh + (size_t)(r * 32 + srow) * 2048 + nkv + gcol, lv + r * 2048);
      }
    }
    const u16* cK = sK[it & 1];
    const u16* cV = sV[it & 1];

    // S = Q K^T
    f32x4 s[4];
#pragma unroll
    for (int nj = 0; nj < 4; ++nj) s[nj] = (f32x4){0.f, 0.f, 0.f, 0.f};
#pragma unroll
    for (int kk = 0; kk < 64; kk += 32) {
      const int c8 = (kk >> 3) + lq;
      bf16x8 kf[4];
#pragma unroll
      for (int nj = 0; nj < 4; ++nj) kf[nj] = ldsfrag(cK, nj * 16 + lr, c8);
#pragma unroll
      for (int nj = 0; nj < 4; ++nj)
        s[nj] = __builtin_amdgcn_mfma_f32_16x16x32_bf16(qreg[kk >> 5], kf[nj], s[nj], 0, 0, 0);
    }

    if (it == qt) {  // diagonal tile mask
      int rloc = w * 16 + lq * 4;
#pragma unroll
      for (int nj = 0; nj < 4; ++nj) {
        int cloc = nj * 16 + lr;
#pragma unroll
        for (int r = 0; r < 4; ++r)
          if (cloc > rloc + r) s[nj][r] = -1e30f;
      }
    }

    // online softmax, exp2 domain
    float al[4];
#pragma unroll
    for (int r = 0; r < 4; ++r) {
      float mx = fmaxf(fmaxf(s[0][r], s[1][r]), fmaxf(s[2][r], s[3][r]));
      mx = red16_max(mx) * L2E;
      float mn = fmaxf(mL2[r], mx);
      al[r] = fexp2(mL2[r] - mn);
      mL2[r] = mn;
    }
#pragma unroll
    for (int nj = 0; nj < 4; ++nj)
#pragma unroll
      for (int r = 0; r < 4; ++r) o[nj][r] *= al[r];
    float rs[4];
#pragma unroll
    for (int r = 0; r < 4; ++r) rs[r] = 0.f;
#pragma unroll
    for (int nj = 0; nj < 4; ++nj)
#pragma unroll
      for (int r = 0; r < 4; ++r) {
        float p = fexp2(fmaf(s[nj][r], L2E, -mL2[r]));
        s[nj][r] = p;
        rs[r] += p;
      }
#pragma unroll
    for (int r = 0; r < 4; ++r) lrow[r] = lrow[r] * al[r] + red16_sum(rs[r]);

    // P -> sP (own wave's rows; swizzled, conflict-free)
#pragma unroll
    for (int nj = 0; nj < 4; ++nj) {
      int chunk = nj * 2 + (lr >> 3);
#pragma unroll
      for (int r = 0; r < 4; ++r) {
        int row = w * 16 + lq * 4 + r;
        sP[row * 64 + ((chunk ^ (row & 7)) << 3) + (lr & 7)] = f2bf_fast(s[nj][r]);
      }
    }
    asm volatile("s_waitcnt lgkmcnt(0)" ::: "memory");

    // O += P V
#pragma unroll
    for (int kk = 0; kk < 64; kk += 32) {
      const int c8 = (kk >> 3) + lq;
      bf16x8 pa = ldsfrag(sP, w * 16 + lr, c8);
      bf16x8 vf[4];
#pragma unroll
      for (int nj = 0; nj < 4; ++nj) vf[nj] = ldsfrag(cV, nj * 16 + lr, c8);
#pragma unroll
      for (int nj = 0; nj < 4; ++nj)
        o[nj] = __builtin_amdgcn_mfma_f32_16x16x32_bf16(pa, vf[nj], o[nj], 0, 0, 0);
    }
  }

  // y[b][t][h*64+hd] bf16
  const int b = bh >> 4, h = bh & 15;
#pragma unroll
  for (int r = 0; r < 4; ++r) {
    float inv = 1.0f / lrow[r];
    int row = q0 + w * 16 + lq * 4 + r;
    size_t base = ((size_t)(b * 2048 + row)) * 1024 + h * 64;
#pragma unroll
    for (int nj = 0; nj < 4; ++nj) yb[base + nj * 16 + lr] = f2bf(o[nj][r] * inv);
  }
}

// ---------------- GEMM2: out = y @ W_proj + b, 64x128 tiles -> 512 blocks ----------------
// B = WpT is 2MB -> x64 re-reads stay L2-resident; 2 blocks/CU vs round-5's 1.
__global__ __launch_bounds__(256) void k_gemm_proj(const u16* __restrict__ ybuf,
                                                   const u16* __restrict__ Wt,
                                                   const float* __restrict__ bias,
                                                   float* __restrict__ out) {
  __shared__ u16 sA[64 * 64], sB[128 * 64];
  f32x4 acc[2][4];
#pragma unroll
  for (int mi = 0; mi < 2; ++mi)
#pragma unroll
    for (int ni = 0; ni < 4; ++ni) acc[mi][ni] = (f32x4){0.f, 0.f, 0.f, 0.f};

  const int m0 = blockIdx.y * 64, n0 = blockIdx.x * 128;
  const int tid = threadIdx.x;
  const int lane = tid & 63, w = tid >> 6;
  const int wm = (w >> 1) << 5, wn = (w & 1) << 6;  // wave tile 32x64
  const int lr = lane & 15, lq = lane >> 4;
  const int srow = tid >> 3;
  const int gcol = ((tid & 7) ^ (srow & 7)) << 3;
  const u16* ag = ybuf + (size_t)(m0 + srow) * 1024 + gcol;
  const u16* bg = Wt + (size_t)(n0 + srow) * 1024 + gcol;
  u16* la = sA + w * 512;
  u16* lb = sB + w * 512;

  for (int k0 = 0; k0 < 1024; k0 += 64) {
    __syncthreads();
#pragma unroll
    for (int r = 0; r < 2; ++r) gld_lds16(ag + (size_t)r * 32 * 1024 + k0, la + r * 2048);
#pragma unroll
    for (int r = 0; r < 4; ++r) gld_lds16(bg + (size_t)r * 32 * 1024 + k0, lb + r * 2048);
    __syncthreads();
#pragma unroll
    for (int kk = 0; kk < 64; kk += 32) {
      const int c8 = (kk >> 3) + lq;
      bf16x8 af[2], bfr[4];
#pragma unroll
      for (int i = 0; i < 2; ++i) af[i] = ldsfrag(sA, wm + i * 16 + lr, c8);
#pragma unroll
      for (int i = 0; i < 4; ++i) bfr[i] = ldsfrag(sB, wn + i * 16 + lr, c8);
#pragma unroll
      for (int mi = 0; mi < 2; ++mi)
#pragma unroll
        for (int ni = 0; ni < 4; ++ni)
          acc[mi][ni] = __builtin_amdgcn_mfma_f32_16x16x32_bf16(af[mi], bfr[ni], acc[mi][ni], 0, 0, 0);
    }
  }

#pragma unroll
  for (int mi = 0; mi < 2; ++mi) {
    int gm = m0 + wm + mi * 16 + lq * 4;
#pragma unroll
    for (int ni = 0; ni < 4; ++ni) {
      int gn = n0 + wn + ni * 16 + lr;
      float bv = bias[gn];
#pragma unroll
      for (int r = 0; r < 4; ++r) out[(size_t)(gm + r) * 1024 + gn] = acc[mi][ni][r] + bv;
    }
  }
}

extern "C" void kernel_launch(void* const* d_in, const int* in_sizes, int n_in,
                              void* d_out, int out_size, void* d_ws, size_t ws_size,
                              hipStream_t stream) {
  const float* x = (const float*)d_in[0];       // [2,2048,1024]
  const float* W_attn = (const float*)d_in[1];  // [1024,3072]
  const float* b_attn = (const float*)d_in[2];  // [3072]
  const float* W_proj = (const float*)d_in[3];  // [1024,1024]
  const float* b_proj = (const float*)d_in[4];  // [1024]
  float* out = (float*)d_out;                   // [2,2048,1024] fp32

  u16* ws = (u16*)d_ws;
  u16* xb = ws;                   // 4096x1024 bf16
  u16* WaT = ws + 4194304;        // 3072x1024 (W_attn^T)
  u16* WpT = ws + 7340032;        // 1024x1024 (W_proj^T)
  u16* qbuf = ws + 8388608;       // [32][2048][64]
  u16* kbuf = ws + 12582912;      // [32][2048][64]
  u16* vtb = ws + 16777216;       // [32][64][2048]
  u16* ybuf = ws + 20971520;      // [4096][1024]

  k_prep<<<dim3(3072), dim3(256), 0, stream>>>(x, xb, W_attn, WaT, W_proj, WpT);
  k_gemm_qkv<<<dim3(768), dim3(256), 0, stream>>>(xb, WaT, b_attn, qbuf, kbuf, vtb);
  k_attn<<<dim3(1024), dim3(256), 0, stream>>>(qbuf, kbuf, vtb, ybuf);
  k_gemm_proj<<<dim3(8, 64), dim3(256), 0, stream>>>(ybuf, WpT, b_proj, out);
}